// Round 2
// baseline (232.957 us; speedup 1.0000x reference)
//
#include <hip/hip_runtime.h>

// Heat2D: B=C=H=W=KD=64. All big matmuls via split-bf16 (hi/lo) MFMA,
// LN folded into matmul epilogues where possible.
//   Layout note: planes and all [c][h][w] transposed buffers are PADDED by
//   256B per 64x64 plane (stride 4160 floats, not 4096) to break power-of-2
//   channel camping (r1: k_k effective HBM BW was stuck at 2.2 TB/s).
//   k_k / k_out: 4 consecutive h per block, 2-deep software pipeline
//   (loads for h+2 issued while computing h), B fragments in registers.
//   k_spec: one wave per (b,c) plane, zero barriers (unchanged from r1).

#define PL_ST 4160   // padded plane stride (floats)
#define TC_ST 4160   // padded per-c stride for [c][h][w] buffers (floats)

typedef __attribute__((ext_vector_type(8))) short short8;
typedef __attribute__((ext_vector_type(4))) float f32x4;
typedef __attribute__((ext_vector_type(4))) unsigned short us4;

__device__ __forceinline__ unsigned short bfhi(float f) {
    return (unsigned short)(__builtin_bit_cast(unsigned int, f) >> 16);
}
__device__ __forceinline__ float hif(float f) {
    return __builtin_bit_cast(float, __builtin_bit_cast(unsigned int, f) & 0xFFFF0000u);
}
// swizzled byte address in 64x64 bf16 row-major buffer (128B rows, 16B chunks
// XOR'd with row&7): bank-uniform for b128 frag reads and b64/u16 writes.
__device__ __forceinline__ int swa(int row, int col) {
    return (row << 7) + (((col >> 3) ^ (row & 7)) << 4) + ((col & 7) << 1);
}
__device__ __forceinline__ short8 fragrd(const short* buf, int row, int kc) {
    int a = (row << 7) + ((kc ^ (row & 7)) << 4);
    return *(const short8*)((const char*)buf + a);
}
// 3-term split-bf16 product accumulate: ah*bh + ah*bl + al*bh
__device__ __forceinline__ f32x4 mm3(short8 ah, short8 al, short8 bh, short8 bl, f32x4 acc) {
    acc = __builtin_amdgcn_mfma_f32_16x16x32_bf16(ah, bh, acc, 0, 0, 0);
    acc = __builtin_amdgcn_mfma_f32_16x16x32_bf16(ah, bl, acc, 0, 0, 0);
    acc = __builtin_amdgcn_mfma_f32_16x16x32_bf16(al, bh, acc, 0, 0, 0);
    return acc;
}

// 64x64x64 matmul, 4 waves: wave computes 32x32 quadrant (2x2 16x16 tiles).
// D[m][n] = sum_k A[m][k]*B^T[n][k], 3-term split-bf16. (used by k_pre2)
__device__ __forceinline__ void mm_block(const short* Ah, const short* Al,
                                         const short* Bh, const short* Bl,
                                         int m0, int n0, int l15, int q,
                                         f32x4 (&acc)[2][2]) {
    const f32x4 zero = {0.f, 0.f, 0.f, 0.f};
    acc[0][0] = zero; acc[0][1] = zero; acc[1][0] = zero; acc[1][1] = zero;
    #pragma unroll
    for (int kb = 0; kb < 2; ++kb) {
        int kc = (kb << 2) + q;
        short8 a0h = fragrd(Ah, m0 + l15, kc);
        short8 a0l = fragrd(Al, m0 + l15, kc);
        short8 a1h = fragrd(Ah, m0 + 16 + l15, kc);
        short8 a1l = fragrd(Al, m0 + 16 + l15, kc);
        short8 b0h = fragrd(Bh, n0 + l15, kc);
        short8 b0l = fragrd(Bl, n0 + l15, kc);
        short8 b1h = fragrd(Bh, n0 + 16 + l15, kc);
        short8 b1l = fragrd(Bl, n0 + 16 + l15, kc);
        acc[0][0] = mm3(a0h, a0l, b0h, b0l, acc[0][0]);
        acc[0][1] = mm3(a0h, a0l, b1h, b1l, acc[0][1]);
        acc[1][0] = mm3(a1h, a1l, b0h, b0l, acc[1][0]);
        acc[1][1] = mm3(a1h, a1l, b1h, b1l, acc[1][1]);
    }
}

// Same quadrant matmul but B fragments already in registers.
__device__ __forceinline__ void mm_block_regB(const short* Ah, const short* Al,
                                              const short8 (&bf)[2][2][2],
                                              int m0, int l15, int q,
                                              f32x4 (&acc)[2][2]) {
    const f32x4 zero = {0.f, 0.f, 0.f, 0.f};
    acc[0][0] = zero; acc[0][1] = zero; acc[1][0] = zero; acc[1][1] = zero;
    #pragma unroll
    for (int kb = 0; kb < 2; ++kb) {
        int kc = (kb << 2) + q;
        short8 a0h = fragrd(Ah, m0 + l15, kc);
        short8 a0l = fragrd(Al, m0 + l15, kc);
        short8 a1h = fragrd(Ah, m0 + 16 + l15, kc);
        short8 a1l = fragrd(Al, m0 + 16 + l15, kc);
        #pragma unroll
        for (int u = 0; u < 2; ++u) {
            acc[0][u] = mm3(a0h, a0l, bf[u][kb][0], bf[u][kb][1], acc[0][u]);
            acc[1][u] = mm3(a1h, a1l, bf[u][kb][0], bf[u][kb][1], acc[1][u]);
        }
    }
}

// ---------------- k_pre1: weights transpose/split + LN-fold vectors + cos ----------------
__global__ __launch_bounds__(256) void k_pre1(
    const float* __restrict__ g_k, const float* __restrict__ b_k,
    const float* __restrict__ Wk, const float* __restrict__ bk,
    const float* __restrict__ g_z, const float* __restrict__ b_z,
    const float* __restrict__ Wz, const float* __restrict__ bz,
    const float* __restrict__ Wo,
    unsigned short* __restrict__ WkTh, unsigned short* __restrict__ WkTl,
    float* __restrict__ su_k, float* __restrict__ v_k,
    unsigned short* __restrict__ WzTh, unsigned short* __restrict__ WzTl,
    float* __restrict__ su_z, float* __restrict__ v_z,
    unsigned short* __restrict__ WoTh, unsigned short* __restrict__ WoTl,
    unsigned short* __restrict__ cos_hi, unsigned short* __restrict__ cos_lo) {
    int t = threadIdx.x;
    if (blockIdx.x < 16) {
        int n = blockIdx.x * 4 + (t >> 6);
        int c = t & 63;
        // Wk' = g_k*Wk
        float wk = Wk[c * 64 + n];
        float a = g_k[c] * wk;
        WkTh[n * 64 + c] = bfhi(a);
        WkTl[n * 64 + c] = bfhi(a - hif(a));
        float sa = a, sv = b_k[c] * wk;
        #pragma unroll
        for (int off = 32; off > 0; off >>= 1) {
            sa += __shfl_xor(sa, off, 64);
            sv += __shfl_xor(sv, off, 64);
        }
        if (c == 0) { su_k[n] = sa; v_k[n] = sv + bk[n]; }
        // Wz' = g_z*Wz
        float wz = Wz[c * 64 + n];
        float az = g_z[c] * wz;
        WzTh[n * 64 + c] = bfhi(az);
        WzTl[n * 64 + c] = bfhi(az - hif(az));
        float saz = az, svz = b_z[c] * wz;
        #pragma unroll
        for (int off = 32; off > 0; off >>= 1) {
            saz += __shfl_xor(saz, off, 64);
            svz += __shfl_xor(svz, off, 64);
        }
        if (c == 0) { su_z[n] = saz; v_z[n] = svz + bz[n]; }
        // Wo^T
        float wo = Wo[c * 64 + n];
        WoTh[n * 64 + c] = bfhi(wo);
        WoTl[n * 64 + c] = bfhi(wo - hif(wo));
    } else {
        int idx = (blockIdx.x - 16) * 256 + t;
        int i = idx >> 6, j = idx & 63;
        float ang = (float)(i * j) * 3.14159265358979323846f * (1.0f / 64.0f);
        float v = cosf(ang) * (1.0f / 64.0f);
        cos_hi[idx] = bfhi(v);
        cos_lo[idx] = bfhi(v - hif(v));
    }
}

// ---------------- k_pre2: z via MFMA (LN folded) + freq transpose ----------------
__global__ __launch_bounds__(256) void k_pre2(
    const float* __restrict__ freq,
    const unsigned short* __restrict__ WzTh_g, const unsigned short* __restrict__ WzTl_g,
    const float* __restrict__ su_z, const float* __restrict__ v_z,
    float* __restrict__ siluzT, float* __restrict__ wexpT,
    float* __restrict__ freqT) {
    __shared__ __align__(16) short Ah[4096], Al[4096], Bh[4096], Bl[4096];
    __shared__ float muS[64], rsS[64];
    __shared__ float tile[64][65];
    int t = threadIdx.x;
    if (blockIdx.x < 64) {
        int h = blockIdx.x;
        // stage B = WzT' swizzled
        #pragma unroll
        for (int p = 0; p < 2; ++p) {
            int e = t + p * 256;
            int row = e >> 3, ch = e & 7;
            int a = (row << 7) + (((ch ^ (row & 7)) << 4));
            *(uint4*)((char*)Bh + a) = *(const uint4*)&WzTh_g[row * 64 + ch * 8];
            *(uint4*)((char*)Bl + a) = *(const uint4*)&WzTl_g[row * 64 + ch * 8];
        }
        // A = freq[h][w][c] (already [w][c] row-major). thread: w=t>>2, 16 c's.
        int w = t >> 2, c0 = (t & 3) << 4;
        float4 fr[4];
        float s1 = 0.f, s2 = 0.f;
        #pragma unroll
        for (int i = 0; i < 4; ++i) {
            fr[i] = *(const float4*)&freq[(h * 64 + w) * 64 + c0 + 4 * i];
            s1 += fr[i].x + fr[i].y + fr[i].z + fr[i].w;
            s2 += fr[i].x * fr[i].x + fr[i].y * fr[i].y + fr[i].z * fr[i].z + fr[i].w * fr[i].w;
        }
        s1 += __shfl_xor(s1, 1, 64); s1 += __shfl_xor(s1, 2, 64);
        s2 += __shfl_xor(s2, 1, 64); s2 += __shfl_xor(s2, 2, 64);
        float mu = s1 * (1.0f / 64.0f);
        float var = s2 * (1.0f / 64.0f) - mu * mu;
        float rs = rsqrtf(var + 1e-5f);
        if ((t & 3) == 0) { muS[w] = mu; rsS[w] = rs; }
        const float* fp = (const float*)fr;
        #pragma unroll
        for (int i = 0; i < 4; ++i) {
            us4 hv, lv;
            #pragma unroll
            for (int r = 0; r < 4; ++r) {
                float f = fp[i * 4 + r];
                hv[r] = bfhi(f);
                lv[r] = bfhi(f - hif(f));
            }
            int a = swa(w, c0 + 4 * i);
            *(us4*)((char*)Ah + a) = hv;
            *(us4*)((char*)Al + a) = lv;
        }
        __syncthreads();
        int lane = t & 63, wv = t >> 6;
        int q = lane >> 4, l15 = lane & 15;
        int m0 = (wv & 1) << 5, n0 = (wv >> 1) << 5;
        f32x4 acc[2][2];
        mm_block(Ah, Al, Bh, Bl, m0, n0, l15, q, acc);
        #pragma unroll
        for (int u = 0; u < 2; ++u) {
            int c = n0 + (u << 4) + l15;
            float suc = su_z[c], vc = v_z[c];
            #pragma unroll
            for (int ti = 0; ti < 2; ++ti) {
                int wb = m0 + (ti << 4) + (q << 2);
                float4 mu4 = *(const float4*)&muS[wb];
                float4 rs4 = *(const float4*)&rsS[wb];
                float4 sil, wx;
                #pragma unroll
                for (int r = 0; r < 4; ++r) {
                    float z = ((const float*)&rs4)[r] * (acc[ti][u][r] - ((const float*)&mu4)[r] * suc) + vc;
                    float lnd = -(float)(h + wb + r) * 0.015625f - 4.1588830833596718565f;
                    ((float*)&sil)[r] = z / (1.0f + expf(-z));
                    ((float*)&wx)[r] = expf(z * lnd);
                }
                size_t base = (size_t)c * TC_ST + h * 64 + wb;
                *(float4*)&siluzT[base] = sil;
                *(float4*)&wexpT[base] = wx;
            }
        }
    } else {
        // freq transpose: freqT[c][h][w] = freq[h][w][c]
        int h = blockIdx.x - 64;
        int w = t >> 2, c0 = (t & 3) << 4;
        #pragma unroll
        for (int i = 0; i < 4; ++i)
            *(float4*)&tile[w][c0 + 4 * i] = *(const float4*)&freq[(h * 64 + w) * 64 + c0 + 4 * i];
        __syncthreads();
        int w0 = (t & 15) << 2;
        #pragma unroll
        for (int p = 0; p < 4; ++p) {
            int c = (t >> 4) + 16 * p;
            float4 fv = make_float4(tile[w0][c], tile[w0 + 1][c], tile[w0 + 2][c], tile[w0 + 3][c]);
            *(float4*)&freqT[(size_t)c * TC_ST + h * 64 + w0] = fv;
        }
    }
}

// ---------------- k_k: planes = LN(x^T+freq)@Wk' (LN folded), 4h/block pipelined ----------------
__global__ __launch_bounds__(256, 3) void k_k(
    const float* __restrict__ x, const float* __restrict__ freqT,
    const unsigned short* __restrict__ WkTh_g, const unsigned short* __restrict__ WkTl_g,
    const float* __restrict__ su_k, const float* __restrict__ v_k,
    float* __restrict__ planes) {
    __shared__ __align__(16) short Ah[2][4096], Al[2][4096];
    __shared__ __align__(16) float red1[4][64], red2[4][64];
    __shared__ float muS[64], rsS[64];
    int b = blockIdx.x >> 4, h0 = (blockIdx.x & 15) << 2;
    int t = threadIdx.x;
    int lane = t & 63, wv = t >> 6;
    int q = lane >> 4, l15 = lane & 15;
    int m0 = (wv & 1) << 5, n0 = (wv >> 1) << 5;
    // B fragments (Wk', LN-folded) -> registers (L2-hot; amortized over 4 h)
    short8 bf[2][2][2];
    #pragma unroll
    for (int u = 0; u < 2; ++u)
        #pragma unroll
        for (int kb = 0; kb < 2; ++kb) {
            int off = (n0 + (u << 4) + l15) * 64 + ((kb << 2) + q) * 8;
            bf[u][kb][0] = *(const short8*)&WkTh_g[off];
            bf[u][kb][1] = *(const short8*)&WkTl_g[off];
        }
    int g = t >> 4, w0 = (t & 15) << 2, c0 = g << 2;
    const float* xb = x + (size_t)b * 262144;
    // 2-deep pipeline: stage loads for h0, h0+1 up front
    float4 xr[2][4], fr[2][4];
    #pragma unroll
    for (int pi = 0; pi < 2; ++pi) {
        int h = h0 + pi;
        #pragma unroll
        for (int i = 0; i < 4; ++i) {
            xr[pi][i] = *(const float4*)&xb[(c0 + i) * 4096 + h * 64 + w0];
            fr[pi][i] = *(const float4*)&freqT[(size_t)(c0 + i) * TC_ST + h * 64 + w0];
        }
    }
    #pragma unroll
    for (int it = 0; it < 4; ++it) {
        int s = it & 1;
        int h = h0 + it;
        // xin = x + freqT; sums
        float4 vv[4];
        float4 s1 = {0, 0, 0, 0}, s2 = {0, 0, 0, 0};
        #pragma unroll
        for (int i = 0; i < 4; ++i) {
            float4 a = xr[s][i], f = fr[s][i];
            a.x += f.x; a.y += f.y; a.z += f.z; a.w += f.w;
            vv[i] = a;
            s1.x += a.x; s1.y += a.y; s1.z += a.z; s1.w += a.w;
            s2.x += a.x * a.x; s2.y += a.y * a.y; s2.z += a.z * a.z; s2.w += a.w * a.w;
        }
        // split + transpose-write A[s] = xinT[w][c]
        const float* vp = (const float*)vv;
        #pragma unroll
        for (int j = 0; j < 4; ++j) {
            us4 hv, lv;
            #pragma unroll
            for (int r = 0; r < 4; ++r) {
                float f = vp[r * 4 + j];
                hv[r] = bfhi(f);
                lv[r] = bfhi(f - hif(f));
            }
            int a = swa(w0 + j, c0);
            *(us4*)((char*)Ah[s] + a) = hv;
            *(us4*)((char*)Al[s] + a) = lv;
        }
        // stats: in-wave shuffle over the wave's 4 c-groups, then 4-deep LDS
        #pragma unroll
        for (int r = 0; r < 4; ++r) {
            float a1 = ((const float*)&s1)[r];
            float a2 = ((const float*)&s2)[r];
            a1 += __shfl_xor(a1, 16, 64); a1 += __shfl_xor(a1, 32, 64);
            a2 += __shfl_xor(a2, 16, 64); a2 += __shfl_xor(a2, 32, 64);
            ((float*)&s1)[r] = a1;
            ((float*)&s2)[r] = a2;
        }
        if (lane < 16) {
            *(float4*)&red1[wv][lane << 2] = s1;
            *(float4*)&red2[wv][lane << 2] = s2;
        }
        __syncthreads();
        if (t < 64) {
            float a1 = red1[0][t] + red1[1][t] + red1[2][t] + red1[3][t];
            float a2 = red2[0][t] + red2[1][t] + red2[2][t] + red2[3][t];
            float mu = a1 * (1.0f / 64.0f);
            float var = a2 * (1.0f / 64.0f) - mu * mu;
            muS[t] = mu; rsS[t] = rsqrtf(var + 1e-5f);
        }
        __syncthreads();
        // prefetch h+2 into the just-consumed slot (hides HBM under MFMA+next split)
        if (it < 2) {
            int hn = h0 + it + 2;
            #pragma unroll
            for (int i = 0; i < 4; ++i) {
                xr[s][i] = *(const float4*)&xb[(c0 + i) * 4096 + hn * 64 + w0];
                fr[s][i] = *(const float4*)&freqT[(size_t)(c0 + i) * TC_ST + hn * 64 + w0];
            }
        }
        f32x4 acc[2][2];
        mm_block_regB(Ah[s], Al[s], bf, m0, l15, q, acc);
        #pragma unroll
        for (int u = 0; u < 2; ++u) {
            int n = n0 + (u << 4) + l15;
            float sun = su_k[n], vn = v_k[n];
            #pragma unroll
            for (int ti = 0; ti < 2; ++ti) {
                int wb = m0 + (ti << 4) + (q << 2);
                float4 mu4 = *(const float4*)&muS[wb];
                float4 rs4 = *(const float4*)&rsS[wb];
                float4 o;
                o.x = rs4.x * (acc[ti][u][0] - mu4.x * sun) + vn;
                o.y = rs4.y * (acc[ti][u][1] - mu4.y * sun) + vn;
                o.z = rs4.z * (acc[ti][u][2] - mu4.z * sun) + vn;
                o.w = rs4.w * (acc[ti][u][3] - mu4.w * sun) + vn;
                *(float4*)&planes[(size_t)(b * 64 + n) * PL_ST + h * 64 + wb] = o;
            }
        }
    }
}

// ---------------- k_spec: spectral transform, ONE WAVE PER PLANE, no barriers ----------------
__global__ __launch_bounds__(128, 2) void k_spec(
    float* __restrict__ planes,
    const unsigned short* __restrict__ cos_hi, const unsigned short* __restrict__ cos_lo,
    const float* __restrict__ wexpT) {
    __shared__ __align__(16) short DhS[2][4096], DlS[2][4096];
    int t = threadIdx.x;
    int wv = t >> 6, lane = t & 63;
    int q = lane >> 4, l15 = lane & 15;
    int pid = blockIdx.x * 2 + wv;
    int c = pid & 63;
    float* po = planes + (size_t)pid * PL_ST;
    const float* wx = wexpT + (size_t)c * TC_ST;
    short* dh = DhS[wv];
    short* dl = DlS[wv];

    // cos fragments -> registers. C is symmetric, so the same 16 fragments
    // serve as B in M1/M2/M4 and as A in M3.
    short8 cf[4][2][2];
    #pragma unroll
    for (int rg = 0; rg < 4; ++rg)
        #pragma unroll
        for (int kb = 0; kb < 2; ++kb) {
            int off = (rg * 16 + l15) * 64 + ((kb << 2) + q) * 8;
            cf[rg][kb][0] = *(const short8*)&cos_hi[off];
            cf[rg][kb][1] = *(const short8*)&cos_lo[off];
        }

    // stage D = P^T (lane owns row w=lane), split hi/lo, swizzled
    #pragma unroll
    for (int jg = 0; jg < 16; ++jg) {
        float f0 = po[(jg * 4 + 0) * 64 + lane];
        float f1 = po[(jg * 4 + 1) * 64 + lane];
        float f2 = po[(jg * 4 + 2) * 64 + lane];
        float f3 = po[(jg * 4 + 3) * 64 + lane];
        us4 hv, lv;
        hv[0] = bfhi(f0); lv[0] = bfhi(f0 - hif(f0));
        hv[1] = bfhi(f1); lv[1] = bfhi(f1 - hif(f1));
        hv[2] = bfhi(f2); lv[2] = bfhi(f2 - hif(f2));
        hv[3] = bfhi(f3); lv[3] = bfhi(f3 - hif(f3));
        int a = swa(lane, jg << 2);
        *(us4*)((char*)dh + a) = hv;
        *(us4*)((char*)dl + a) = lv;
    }

    short8 af[4][2][2];
    f32x4 acc[2][2];
    const f32x4 zacc = {0.f, 0.f, 0.f, 0.f};

    // All LDS reads of a pass happen here, BEFORE any in-place write-back
    // (WAR safety for the single per-wave buffer; DS ops are wave-ordered).
#define LOAD_AF()                                                            \
    _Pragma("unroll")                                                        \
    for (int rg = 0; rg < 4; ++rg) {                                         \
        _Pragma("unroll")                                                    \
        for (int kb = 0; kb < 2; ++kb) {                                     \
            af[rg][kb][0] = fragrd(dh, rg * 16 + l15, (kb << 2) + q);        \
            af[rg][kb][1] = fragrd(dl, rg * 16 + l15, (kb << 2) + q);        \
        }                                                                    \
    }

#define QMM(ASRC, BSRC)                                                      \
    acc[0][0] = zacc; acc[0][1] = zacc; acc[1][0] = zacc; acc[1][1] = zacc;  \
    __builtin_amdgcn_s_setprio(1);                                           \
    _Pragma("unroll")                                                        \
    for (int kb = 0; kb < 2; ++kb)                                           \
        _Pragma("unroll")                                                    \
        for (int ti = 0; ti < 2; ++ti)                                       \
            _Pragma("unroll")                                                \
            for (int u = 0; u < 2; ++u)                                      \
                acc[ti][u] = mm3(ASRC[2 * mq + ti][kb][0], ASRC[2 * mq + ti][kb][1], \
                                 BSRC[2 * nq + u][kb][0], BSRC[2 * nq + u][kb][1],   \
                                 acc[ti][u]);                                \
    __builtin_amdgcn_s_setprio(0);

#define WB_T()                                                               \
    _Pragma("unroll")                                                        \
    for (int ti = 0; ti < 2; ++ti)                                           \
        _Pragma("unroll")                                                    \
        for (int u = 0; u < 2; ++u) {                                        \
            int row = (nq << 5) + (u << 4) + l15;                            \
            int col = (mq << 5) + (ti << 4) + (q << 2);                      \
            int a = swa(row, col);                                           \
            us4 hv, lv;                                                      \
            _Pragma("unroll")                                                \
            for (int r = 0; r < 4; ++r) {                                    \
                float f = acc[ti][u][r];                                     \
                hv[r] = bfhi(f);                                             \
                lv[r] = bfhi(f - hif(f));                                    \
            }                                                                \
            *(us4*)((char*)dh + a) = hv;                                     \
            *(us4*)((char*)dl + a) = lv;                                     \
        }

    // ---- M1: D <- (D*C^T)^T   (D becomes C*P)
    LOAD_AF()
    #pragma unroll
    for (int mq = 0; mq < 2; ++mq)
        #pragma unroll
        for (int nq = 0; nq < 2; ++nq) {
            QMM(af, cf)
            WB_T()
        }

    // ---- M2: D <- ((D*C^T) .* W)^T   (gate C*P*C^T with wexp)
    LOAD_AF()
    #pragma unroll
    for (int mq = 0; mq < 2; ++mq)
        #pragma unroll
        for (int nq = 0; nq < 2; ++nq) {
            float wxr[2][2][4];
            #pragma unroll
            for (int ti = 0; ti < 2; ++ti)
                #pragma unroll
                for (int u = 0; u < 2; ++u)
                    #pragma unroll
                    for (int r = 0; r < 4; ++r)
                        wxr[ti][u][r] = wx[((mq << 5) + (ti << 4) + (q << 2) + r) * 64
                                           + (nq << 5) + (u << 4) + l15];
            QMM(af, cf)
            #pragma unroll
            for (int ti = 0; ti < 2; ++ti)
                #pragma unroll
                for (int u = 0; u < 2; ++u)
                    #pragma unroll
                    for (int r = 0; r < 4; ++r)
                        acc[ti][u][r] *= wxr[ti][u][r];
            WB_T()
        }

    // ---- M3: D <- C*D^T (row-major u16 scatter)
    LOAD_AF()
    #pragma unroll
    for (int mq = 0; mq < 2; ++mq)
        #pragma unroll
        for (int nq = 0; nq < 2; ++nq) {
            QMM(cf, af)
            #pragma unroll
            for (int ti = 0; ti < 2; ++ti)
                #pragma unroll
                for (int u = 0; u < 2; ++u)
                    #pragma unroll
                    for (int r = 0; r < 4; ++r) {
                        int row = (mq << 5) + (ti << 4) + (q << 2) + r;
                        int col = (nq << 5) + (u << 4) + l15;
                        int a = swa(row, col);
                        float f = acc[ti][u][r];
                        *(unsigned short*)((char*)dh + a) = bfhi(f);
                        *(unsigned short*)((char*)dl + a) = bfhi(f - hif(f));
                    }
        }

    // ---- M4: po <- D*C^T (in place to global)
    LOAD_AF()
    #pragma unroll
    for (int mq = 0; mq < 2; ++mq)
        #pragma unroll
        for (int nq = 0; nq < 2; ++nq) {
            QMM(af, cf)
            #pragma unroll
            for (int ti = 0; ti < 2; ++ti)
                #pragma unroll
                for (int u = 0; u < 2; ++u)
                    #pragma unroll
                    for (int r = 0; r < 4; ++r) {
                        int h = (mq << 5) + (ti << 4) + (q << 2) + r;
                        int w = (nq << 5) + (u << 4) + l15;
                        po[h * 64 + w] = acc[ti][u][r];
                    }
        }
#undef LOAD_AF
#undef QMM
#undef WB_T
}

// ---------------- k_out: out = ((LN(t)*g_o+b_o)*siluz)@Wo + bo, 4h/block pipelined ----------------
__global__ __launch_bounds__(256, 3) void k_out(
    const float* __restrict__ planes, const float* __restrict__ siluzT,
    const float* __restrict__ g_o, const float* __restrict__ b_o,
    const unsigned short* __restrict__ WoTh_g, const unsigned short* __restrict__ WoTl_g,
    const float* __restrict__ bo, float* __restrict__ out) {
    __shared__ __align__(16) short Ah[2][4096], Al[2][4096];
    __shared__ __align__(16) float red1[4][64], red2[4][64];
    __shared__ float muS[64], rsS[64];
    int b = blockIdx.x >> 4, h0 = (blockIdx.x & 15) << 2;
    int t = threadIdx.x;
    int lane = t & 63, wv = t >> 6;
    int q = lane >> 4, l15 = lane & 15;
    int m0 = (wv & 1) << 5, n0 = (wv >> 1) << 5;
    // B fragments (Wo^T) -> registers
    short8 bf[2][2][2];
    #pragma unroll
    for (int u = 0; u < 2; ++u)
        #pragma unroll
        for (int kb = 0; kb < 2; ++kb) {
            int off = (n0 + (u << 4) + l15) * 64 + ((kb << 2) + q) * 8;
            bf[u][kb][0] = *(const short8*)&WoTh_g[off];
            bf[u][kb][1] = *(const short8*)&WoTl_g[off];
        }
    int g = t >> 4, w0 = (t & 15) << 2, c0 = g << 2;
    float4 pr[2][4], sz[2][4];
    #pragma unroll
    for (int pi = 0; pi < 2; ++pi) {
        int h = h0 + pi;
        #pragma unroll
        for (int i = 0; i < 4; ++i) {
            pr[pi][i] = *(const float4*)&planes[(size_t)(b * 64 + c0 + i) * PL_ST + h * 64 + w0];
            sz[pi][i] = *(const float4*)&siluzT[(size_t)(c0 + i) * TC_ST + h * 64 + w0];
        }
    }
    #pragma unroll
    for (int it = 0; it < 4; ++it) {
        int s = it & 1;
        int h = h0 + it;
        float4 s1 = {0, 0, 0, 0}, s2 = {0, 0, 0, 0};
        #pragma unroll
        for (int i = 0; i < 4; ++i) {
            float4 tv = pr[s][i];
            s1.x += tv.x; s1.y += tv.y; s1.z += tv.z; s1.w += tv.w;
            s2.x += tv.x * tv.x; s2.y += tv.y * tv.y;
            s2.z += tv.z * tv.z; s2.w += tv.w * tv.w;
        }
        #pragma unroll
        for (int r = 0; r < 4; ++r) {
            float a1 = ((const float*)&s1)[r];
            float a2 = ((const float*)&s2)[r];
            a1 += __shfl_xor(a1, 16, 64); a1 += __shfl_xor(a1, 32, 64);
            a2 += __shfl_xor(a2, 16, 64); a2 += __shfl_xor(a2, 32, 64);
            ((float*)&s1)[r] = a1;
            ((float*)&s2)[r] = a2;
        }
        if (lane < 16) {
            *(float4*)&red1[wv][lane << 2] = s1;
            *(float4*)&red2[wv][lane << 2] = s2;
        }
        __syncthreads();
        if (t < 64) {
            float a1 = red1[0][t] + red1[1][t] + red1[2][t] + red1[3][t];
            float a2 = red2[0][t] + red2[1][t] + red2[2][t] + red2[3][t];
            float mu = a1 * (1.0f / 64.0f);
            float var = a2 * (1.0f / 64.0f) - mu * mu;
            muS[t] = mu; rsS[t] = rsqrtf(var + 1e-5f);
        }
        __syncthreads();
        // gate + split + transpose-write A[s]
        {
            float4 mu4 = *(const float4*)&muS[w0];
            float4 rs4 = *(const float4*)&rsS[w0];
            float4 vr[4];
            #pragma unroll
            for (int i = 0; i < 4; ++i) {
                int cc = c0 + i;
                float go = g_o[cc], boc = b_o[cc];
                float4 tv = pr[s][i], sv = sz[s][i];
                vr[i].x = ((tv.x - mu4.x) * rs4.x * go + boc) * sv.x;
                vr[i].y = ((tv.y - mu4.y) * rs4.y * go + boc) * sv.y;
                vr[i].z = ((tv.z - mu4.z) * rs4.z * go + boc) * sv.z;
                vr[i].w = ((tv.w - mu4.w) * rs4.w * go + boc) * sv.w;
            }
            const float* vp = (const float*)vr;
            #pragma unroll
            for (int j = 0; j < 4; ++j) {
                us4 hv, lv;
                #pragma unroll
                for (int r = 0; r < 4; ++r) {
                    float f = vp[r * 4 + j];
                    hv[r] = bfhi(f);
                    lv[r] = bfhi(f - hif(f));
                }
                int a = swa(w0 + j, c0);
                *(us4*)((char*)Ah[s] + a) = hv;
                *(us4*)((char*)Al[s] + a) = lv;
            }
        }
        // prefetch h+2 into the just-consumed slot
        if (it < 2) {
            int hn = h0 + it + 2;
            #pragma unroll
            for (int i = 0; i < 4; ++i) {
                pr[s][i] = *(const float4*)&planes[(size_t)(b * 64 + c0 + i) * PL_ST + hn * 64 + w0];
                sz[s][i] = *(const float4*)&siluzT[(size_t)(c0 + i) * TC_ST + hn * 64 + w0];
            }
        }
        __syncthreads();
        f32x4 acc[2][2];
        mm_block_regB(Ah[s], Al[s], bf, m0, l15, q, acc);
        #pragma unroll
        for (int u = 0; u < 2; ++u) {
            int o_ = n0 + (u << 4) + l15;
            float bov = bo[o_];
            #pragma unroll
            for (int ti = 0; ti < 2; ++ti) {
                int wb = m0 + (ti << 4) + (q << 2);
                float4 o;
                o.x = acc[ti][u][0] + bov;
                o.y = acc[ti][u][1] + bov;
                o.z = acc[ti][u][2] + bov;
                o.w = acc[ti][u][3] + bov;
                *(float4*)&out[((size_t)(b * 64 + o_) * 64 + h) * 64 + wb] = o;
            }
        }
    }
}

extern "C" void kernel_launch(void* const* d_in, const int* in_sizes, int n_in,
                              void* d_out, int out_size, void* d_ws, size_t ws_size,
                              hipStream_t stream) {
    const float* x    = (const float*)d_in[0];
    const float* freq = (const float*)d_in[1];
    const float* g_k  = (const float*)d_in[2];
    const float* b_k  = (const float*)d_in[3];
    const float* Wk   = (const float*)d_in[4];
    const float* bk   = (const float*)d_in[5];
    const float* g_z  = (const float*)d_in[6];
    const float* b_z  = (const float*)d_in[7];
    const float* Wz   = (const float*)d_in[8];
    const float* bz   = (const float*)d_in[9];
    const float* g_o  = (const float*)d_in[10];
    const float* b_o  = (const float*)d_in[11];
    const float* Wo   = (const float*)d_in[12];
    const float* bo   = (const float*)d_in[13];
    float* out = (float*)d_out;

    float* ws = (float*)d_ws;
    float* planes = ws;                                   // 4096*PL_ST f
    float* siluzT = planes + (size_t)4096 * PL_ST;        // 64*TC_ST f
    float* wexpT  = siluzT + (size_t)64 * TC_ST;
    float* freqT  = wexpT + (size_t)64 * TC_ST;
    float* su_k   = freqT + (size_t)64 * TC_ST;           // 64
    float* v_k    = su_k + 64;
    float* su_z   = v_k + 64;
    float* v_z    = su_z + 64;
    unsigned short* cos_hi = (unsigned short*)(v_z + 64); // 4096 u16 each
    unsigned short* cos_lo = cos_hi + 4096;
    unsigned short* WkTh = cos_lo + 4096;
    unsigned short* WkTl = WkTh + 4096;
    unsigned short* WzTh = WkTl + 4096;
    unsigned short* WzTl = WzTh + 4096;
    unsigned short* WoTh = WzTl + 4096;
    unsigned short* WoTl = WoTh + 4096;

    k_pre1<<<32, 256, 0, stream>>>(g_k, b_k, Wk, bk, g_z, b_z, Wz, bz, Wo,
                                   WkTh, WkTl, su_k, v_k, WzTh, WzTl, su_z, v_z,
                                   WoTh, WoTl, cos_hi, cos_lo);
    k_pre2<<<128, 256, 0, stream>>>(freq, WzTh, WzTl, su_z, v_z, siluzT, wexpT, freqT);
    k_k<<<1024, 256, 0, stream>>>(x, freqT, WkTh, WkTl, su_k, v_k, planes);
    k_spec<<<2048, 128, 0, stream>>>(planes, cos_hi, cos_lo, wexpT);
    k_out<<<1024, 256, 0, stream>>>(planes, siluzT, g_o, b_o, WoTh, WoTl, bo, out);
}

// Round 3
// 228.795 us; speedup vs baseline: 1.0182x; 1.0182x over previous
//
#include <hip/hip_runtime.h>

// Heat2D: B=C=H=W=KD=64. All big matmuls via split-bf16 (hi/lo) MFMA,
// LN folded into matmul epilogues where possible.
//   Layout: planes and [c][h][w] buffers padded (stride 4160 floats) to break
//   power-of-2 channel camping (r2: k_k+k_out dropped ~46+40 -> ~30-35 total).
//   k_k / k_out: 4 consecutive h per block, 2-deep software pipeline,
//   B fragments in registers (r2, kept).
//   k_spec: 4 waves per (b,c) plane (r0 structure), SINGLE in-place D buffer
//   (loads->barrier->MFMA+WB->barrier per phase), cos in LDS, gate
//   prefetched to regs. 32KB LDS -> 4 blocks/CU, 16 waves/CU.

#define PL_ST 4160   // padded plane stride (floats)
#define TC_ST 4160   // padded per-c stride for [c][h][w] buffers (floats)

typedef __attribute__((ext_vector_type(8))) short short8;
typedef __attribute__((ext_vector_type(4))) float f32x4;
typedef __attribute__((ext_vector_type(4))) unsigned short us4;

__device__ __forceinline__ unsigned short bfhi(float f) {
    return (unsigned short)(__builtin_bit_cast(unsigned int, f) >> 16);
}
__device__ __forceinline__ float hif(float f) {
    return __builtin_bit_cast(float, __builtin_bit_cast(unsigned int, f) & 0xFFFF0000u);
}
// swizzled byte address in 64x64 bf16 row-major buffer (128B rows, 16B chunks
// XOR'd with row&7): bank-uniform for b128 frag reads and b64/u16 writes.
__device__ __forceinline__ int swa(int row, int col) {
    return (row << 7) + (((col >> 3) ^ (row & 7)) << 4) + ((col & 7) << 1);
}
__device__ __forceinline__ short8 fragrd(const short* buf, int row, int kc) {
    int a = (row << 7) + ((kc ^ (row & 7)) << 4);
    return *(const short8*)((const char*)buf + a);
}
// 3-term split-bf16 product accumulate: ah*bh + ah*bl + al*bh
__device__ __forceinline__ f32x4 mm3(short8 ah, short8 al, short8 bh, short8 bl, f32x4 acc) {
    acc = __builtin_amdgcn_mfma_f32_16x16x32_bf16(ah, bh, acc, 0, 0, 0);
    acc = __builtin_amdgcn_mfma_f32_16x16x32_bf16(ah, bl, acc, 0, 0, 0);
    acc = __builtin_amdgcn_mfma_f32_16x16x32_bf16(al, bh, acc, 0, 0, 0);
    return acc;
}

// 64x64x64 matmul, 4 waves: wave computes 32x32 quadrant (2x2 16x16 tiles).
// D[m][n] = sum_k A[m][k]*B^T[n][k], 3-term split-bf16. (used by k_pre2)
__device__ __forceinline__ void mm_block(const short* Ah, const short* Al,
                                         const short* Bh, const short* Bl,
                                         int m0, int n0, int l15, int q,
                                         f32x4 (&acc)[2][2]) {
    const f32x4 zero = {0.f, 0.f, 0.f, 0.f};
    acc[0][0] = zero; acc[0][1] = zero; acc[1][0] = zero; acc[1][1] = zero;
    #pragma unroll
    for (int kb = 0; kb < 2; ++kb) {
        int kc = (kb << 2) + q;
        short8 a0h = fragrd(Ah, m0 + l15, kc);
        short8 a0l = fragrd(Al, m0 + l15, kc);
        short8 a1h = fragrd(Ah, m0 + 16 + l15, kc);
        short8 a1l = fragrd(Al, m0 + 16 + l15, kc);
        short8 b0h = fragrd(Bh, n0 + l15, kc);
        short8 b0l = fragrd(Bl, n0 + l15, kc);
        short8 b1h = fragrd(Bh, n0 + 16 + l15, kc);
        short8 b1l = fragrd(Bl, n0 + 16 + l15, kc);
        acc[0][0] = mm3(a0h, a0l, b0h, b0l, acc[0][0]);
        acc[0][1] = mm3(a0h, a0l, b1h, b1l, acc[0][1]);
        acc[1][0] = mm3(a1h, a1l, b0h, b0l, acc[1][0]);
        acc[1][1] = mm3(a1h, a1l, b1h, b1l, acc[1][1]);
    }
}

// Same quadrant matmul but B fragments already in registers.
__device__ __forceinline__ void mm_block_regB(const short* Ah, const short* Al,
                                              const short8 (&bf)[2][2][2],
                                              int m0, int l15, int q,
                                              f32x4 (&acc)[2][2]) {
    const f32x4 zero = {0.f, 0.f, 0.f, 0.f};
    acc[0][0] = zero; acc[0][1] = zero; acc[1][0] = zero; acc[1][1] = zero;
    #pragma unroll
    for (int kb = 0; kb < 2; ++kb) {
        int kc = (kb << 2) + q;
        short8 a0h = fragrd(Ah, m0 + l15, kc);
        short8 a0l = fragrd(Al, m0 + l15, kc);
        short8 a1h = fragrd(Ah, m0 + 16 + l15, kc);
        short8 a1l = fragrd(Al, m0 + 16 + l15, kc);
        #pragma unroll
        for (int u = 0; u < 2; ++u) {
            acc[0][u] = mm3(a0h, a0l, bf[u][kb][0], bf[u][kb][1], acc[0][u]);
            acc[1][u] = mm3(a1h, a1l, bf[u][kb][0], bf[u][kb][1], acc[1][u]);
        }
    }
}

// ---------------- k_pre1: weights transpose/split + LN-fold vectors + cos ----------------
__global__ __launch_bounds__(256) void k_pre1(
    const float* __restrict__ g_k, const float* __restrict__ b_k,
    const float* __restrict__ Wk, const float* __restrict__ bk,
    const float* __restrict__ g_z, const float* __restrict__ b_z,
    const float* __restrict__ Wz, const float* __restrict__ bz,
    const float* __restrict__ Wo,
    unsigned short* __restrict__ WkTh, unsigned short* __restrict__ WkTl,
    float* __restrict__ su_k, float* __restrict__ v_k,
    unsigned short* __restrict__ WzTh, unsigned short* __restrict__ WzTl,
    float* __restrict__ su_z, float* __restrict__ v_z,
    unsigned short* __restrict__ WoTh, unsigned short* __restrict__ WoTl,
    unsigned short* __restrict__ cos_hi, unsigned short* __restrict__ cos_lo) {
    int t = threadIdx.x;
    if (blockIdx.x < 16) {
        int n = blockIdx.x * 4 + (t >> 6);
        int c = t & 63;
        // Wk' = g_k*Wk
        float wk = Wk[c * 64 + n];
        float a = g_k[c] * wk;
        WkTh[n * 64 + c] = bfhi(a);
        WkTl[n * 64 + c] = bfhi(a - hif(a));
        float sa = a, sv = b_k[c] * wk;
        #pragma unroll
        for (int off = 32; off > 0; off >>= 1) {
            sa += __shfl_xor(sa, off, 64);
            sv += __shfl_xor(sv, off, 64);
        }
        if (c == 0) { su_k[n] = sa; v_k[n] = sv + bk[n]; }
        // Wz' = g_z*Wz
        float wz = Wz[c * 64 + n];
        float az = g_z[c] * wz;
        WzTh[n * 64 + c] = bfhi(az);
        WzTl[n * 64 + c] = bfhi(az - hif(az));
        float saz = az, svz = b_z[c] * wz;
        #pragma unroll
        for (int off = 32; off > 0; off >>= 1) {
            saz += __shfl_xor(saz, off, 64);
            svz += __shfl_xor(svz, off, 64);
        }
        if (c == 0) { su_z[n] = saz; v_z[n] = svz + bz[n]; }
        // Wo^T
        float wo = Wo[c * 64 + n];
        WoTh[n * 64 + c] = bfhi(wo);
        WoTl[n * 64 + c] = bfhi(wo - hif(wo));
    } else {
        int idx = (blockIdx.x - 16) * 256 + t;
        int i = idx >> 6, j = idx & 63;
        float ang = (float)(i * j) * 3.14159265358979323846f * (1.0f / 64.0f);
        float v = cosf(ang) * (1.0f / 64.0f);
        cos_hi[idx] = bfhi(v);
        cos_lo[idx] = bfhi(v - hif(v));
    }
}

// ---------------- k_pre2: z via MFMA (LN folded) + freq transpose ----------------
__global__ __launch_bounds__(256) void k_pre2(
    const float* __restrict__ freq,
    const unsigned short* __restrict__ WzTh_g, const unsigned short* __restrict__ WzTl_g,
    const float* __restrict__ su_z, const float* __restrict__ v_z,
    float* __restrict__ siluzT, float* __restrict__ wexpT,
    float* __restrict__ freqT) {
    __shared__ __align__(16) short Ah[4096], Al[4096], Bh[4096], Bl[4096];
    __shared__ float muS[64], rsS[64];
    __shared__ float tile[64][65];
    int t = threadIdx.x;
    if (blockIdx.x < 64) {
        int h = blockIdx.x;
        // stage B = WzT' swizzled
        #pragma unroll
        for (int p = 0; p < 2; ++p) {
            int e = t + p * 256;
            int row = e >> 3, ch = e & 7;
            int a = (row << 7) + (((ch ^ (row & 7)) << 4));
            *(uint4*)((char*)Bh + a) = *(const uint4*)&WzTh_g[row * 64 + ch * 8];
            *(uint4*)((char*)Bl + a) = *(const uint4*)&WzTl_g[row * 64 + ch * 8];
        }
        // A = freq[h][w][c] (already [w][c] row-major). thread: w=t>>2, 16 c's.
        int w = t >> 2, c0 = (t & 3) << 4;
        float4 fr[4];
        float s1 = 0.f, s2 = 0.f;
        #pragma unroll
        for (int i = 0; i < 4; ++i) {
            fr[i] = *(const float4*)&freq[(h * 64 + w) * 64 + c0 + 4 * i];
            s1 += fr[i].x + fr[i].y + fr[i].z + fr[i].w;
            s2 += fr[i].x * fr[i].x + fr[i].y * fr[i].y + fr[i].z * fr[i].z + fr[i].w * fr[i].w;
        }
        s1 += __shfl_xor(s1, 1, 64); s1 += __shfl_xor(s1, 2, 64);
        s2 += __shfl_xor(s2, 1, 64); s2 += __shfl_xor(s2, 2, 64);
        float mu = s1 * (1.0f / 64.0f);
        float var = s2 * (1.0f / 64.0f) - mu * mu;
        float rs = rsqrtf(var + 1e-5f);
        if ((t & 3) == 0) { muS[w] = mu; rsS[w] = rs; }
        const float* fp = (const float*)fr;
        #pragma unroll
        for (int i = 0; i < 4; ++i) {
            us4 hv, lv;
            #pragma unroll
            for (int r = 0; r < 4; ++r) {
                float f = fp[i * 4 + r];
                hv[r] = bfhi(f);
                lv[r] = bfhi(f - hif(f));
            }
            int a = swa(w, c0 + 4 * i);
            *(us4*)((char*)Ah + a) = hv;
            *(us4*)((char*)Al + a) = lv;
        }
        __syncthreads();
        int lane = t & 63, wv = t >> 6;
        int q = lane >> 4, l15 = lane & 15;
        int m0 = (wv & 1) << 5, n0 = (wv >> 1) << 5;
        f32x4 acc[2][2];
        mm_block(Ah, Al, Bh, Bl, m0, n0, l15, q, acc);
        #pragma unroll
        for (int u = 0; u < 2; ++u) {
            int c = n0 + (u << 4) + l15;
            float suc = su_z[c], vc = v_z[c];
            #pragma unroll
            for (int ti = 0; ti < 2; ++ti) {
                int wb = m0 + (ti << 4) + (q << 2);
                float4 mu4 = *(const float4*)&muS[wb];
                float4 rs4 = *(const float4*)&rsS[wb];
                float4 sil, wx;
                #pragma unroll
                for (int r = 0; r < 4; ++r) {
                    float z = ((const float*)&rs4)[r] * (acc[ti][u][r] - ((const float*)&mu4)[r] * suc) + vc;
                    float lnd = -(float)(h + wb + r) * 0.015625f - 4.1588830833596718565f;
                    ((float*)&sil)[r] = z / (1.0f + expf(-z));
                    ((float*)&wx)[r] = expf(z * lnd);
                }
                size_t base = (size_t)c * TC_ST + h * 64 + wb;
                *(float4*)&siluzT[base] = sil;
                *(float4*)&wexpT[base] = wx;
            }
        }
    } else {
        // freq transpose: freqT[c][h][w] = freq[h][w][c]
        int h = blockIdx.x - 64;
        int w = t >> 2, c0 = (t & 3) << 4;
        #pragma unroll
        for (int i = 0; i < 4; ++i)
            *(float4*)&tile[w][c0 + 4 * i] = *(const float4*)&freq[(h * 64 + w) * 64 + c0 + 4 * i];
        __syncthreads();
        int w0 = (t & 15) << 2;
        #pragma unroll
        for (int p = 0; p < 4; ++p) {
            int c = (t >> 4) + 16 * p;
            float4 fv = make_float4(tile[w0][c], tile[w0 + 1][c], tile[w0 + 2][c], tile[w0 + 3][c]);
            *(float4*)&freqT[(size_t)c * TC_ST + h * 64 + w0] = fv;
        }
    }
}

// ---------------- k_k: planes = LN(x^T+freq)@Wk' (LN folded), 4h/block pipelined ----------------
__global__ __launch_bounds__(256, 3) void k_k(
    const float* __restrict__ x, const float* __restrict__ freqT,
    const unsigned short* __restrict__ WkTh_g, const unsigned short* __restrict__ WkTl_g,
    const float* __restrict__ su_k, const float* __restrict__ v_k,
    float* __restrict__ planes) {
    __shared__ __align__(16) short Ah[2][4096], Al[2][4096];
    __shared__ __align__(16) float red1[4][64], red2[4][64];
    __shared__ float muS[64], rsS[64];
    int b = blockIdx.x >> 4, h0 = (blockIdx.x & 15) << 2;
    int t = threadIdx.x;
    int lane = t & 63, wv = t >> 6;
    int q = lane >> 4, l15 = lane & 15;
    int m0 = (wv & 1) << 5, n0 = (wv >> 1) << 5;
    // B fragments (Wk', LN-folded) -> registers (L2-hot; amortized over 4 h)
    short8 bf[2][2][2];
    #pragma unroll
    for (int u = 0; u < 2; ++u)
        #pragma unroll
        for (int kb = 0; kb < 2; ++kb) {
            int off = (n0 + (u << 4) + l15) * 64 + ((kb << 2) + q) * 8;
            bf[u][kb][0] = *(const short8*)&WkTh_g[off];
            bf[u][kb][1] = *(const short8*)&WkTl_g[off];
        }
    int g = t >> 4, w0 = (t & 15) << 2, c0 = g << 2;
    const float* xb = x + (size_t)b * 262144;
    // 2-deep pipeline: stage loads for h0, h0+1 up front
    float4 xr[2][4], fr[2][4];
    #pragma unroll
    for (int pi = 0; pi < 2; ++pi) {
        int h = h0 + pi;
        #pragma unroll
        for (int i = 0; i < 4; ++i) {
            xr[pi][i] = *(const float4*)&xb[(c0 + i) * 4096 + h * 64 + w0];
            fr[pi][i] = *(const float4*)&freqT[(size_t)(c0 + i) * TC_ST + h * 64 + w0];
        }
    }
    #pragma unroll
    for (int it = 0; it < 4; ++it) {
        int s = it & 1;
        int h = h0 + it;
        // xin = x + freqT; sums
        float4 vv[4];
        float4 s1 = {0, 0, 0, 0}, s2 = {0, 0, 0, 0};
        #pragma unroll
        for (int i = 0; i < 4; ++i) {
            float4 a = xr[s][i], f = fr[s][i];
            a.x += f.x; a.y += f.y; a.z += f.z; a.w += f.w;
            vv[i] = a;
            s1.x += a.x; s1.y += a.y; s1.z += a.z; s1.w += a.w;
            s2.x += a.x * a.x; s2.y += a.y * a.y; s2.z += a.z * a.z; s2.w += a.w * a.w;
        }
        // split + transpose-write A[s] = xinT[w][c]
        const float* vp = (const float*)vv;
        #pragma unroll
        for (int j = 0; j < 4; ++j) {
            us4 hv, lv;
            #pragma unroll
            for (int r = 0; r < 4; ++r) {
                float f = vp[r * 4 + j];
                hv[r] = bfhi(f);
                lv[r] = bfhi(f - hif(f));
            }
            int a = swa(w0 + j, c0);
            *(us4*)((char*)Ah[s] + a) = hv;
            *(us4*)((char*)Al[s] + a) = lv;
        }
        // stats: in-wave shuffle over the wave's 4 c-groups, then 4-deep LDS
        #pragma unroll
        for (int r = 0; r < 4; ++r) {
            float a1 = ((const float*)&s1)[r];
            float a2 = ((const float*)&s2)[r];
            a1 += __shfl_xor(a1, 16, 64); a1 += __shfl_xor(a1, 32, 64);
            a2 += __shfl_xor(a2, 16, 64); a2 += __shfl_xor(a2, 32, 64);
            ((float*)&s1)[r] = a1;
            ((float*)&s2)[r] = a2;
        }
        if (lane < 16) {
            *(float4*)&red1[wv][lane << 2] = s1;
            *(float4*)&red2[wv][lane << 2] = s2;
        }
        __syncthreads();
        if (t < 64) {
            float a1 = red1[0][t] + red1[1][t] + red1[2][t] + red1[3][t];
            float a2 = red2[0][t] + red2[1][t] + red2[2][t] + red2[3][t];
            float mu = a1 * (1.0f / 64.0f);
            float var = a2 * (1.0f / 64.0f) - mu * mu;
            muS[t] = mu; rsS[t] = rsqrtf(var + 1e-5f);
        }
        __syncthreads();
        // prefetch h+2 into the just-consumed slot (hides HBM under MFMA+next split)
        if (it < 2) {
            int hn = h0 + it + 2;
            #pragma unroll
            for (int i = 0; i < 4; ++i) {
                xr[s][i] = *(const float4*)&xb[(c0 + i) * 4096 + hn * 64 + w0];
                fr[s][i] = *(const float4*)&freqT[(size_t)(c0 + i) * TC_ST + hn * 64 + w0];
            }
        }
        f32x4 acc[2][2];
        mm_block_regB(Ah[s], Al[s], bf, m0, l15, q, acc);
        #pragma unroll
        for (int u = 0; u < 2; ++u) {
            int n = n0 + (u << 4) + l15;
            float sun = su_k[n], vn = v_k[n];
            #pragma unroll
            for (int ti = 0; ti < 2; ++ti) {
                int wb = m0 + (ti << 4) + (q << 2);
                float4 mu4 = *(const float4*)&muS[wb];
                float4 rs4 = *(const float4*)&rsS[wb];
                float4 o;
                o.x = rs4.x * (acc[ti][u][0] - mu4.x * sun) + vn;
                o.y = rs4.y * (acc[ti][u][1] - mu4.y * sun) + vn;
                o.z = rs4.z * (acc[ti][u][2] - mu4.z * sun) + vn;
                o.w = rs4.w * (acc[ti][u][3] - mu4.w * sun) + vn;
                *(float4*)&planes[(size_t)(b * 64 + n) * PL_ST + h * 64 + wb] = o;
            }
        }
    }
}

// ---------------- k_spec: 4 waves/plane, single in-place D buffer ----------------
__global__ __launch_bounds__(256, 4) void k_spec(
    float* __restrict__ planes,
    const unsigned short* __restrict__ cos_hi, const unsigned short* __restrict__ cos_lo,
    const float* __restrict__ wexpT) {
    __shared__ __align__(16) short Ch[4096], Cl[4096];
    __shared__ __align__(16) short Dh[4096], Dl[4096];
    int c = blockIdx.x & 63;
    float* po = planes + (size_t)blockIdx.x * PL_ST;
    const float* wx = wexpT + (size_t)c * TC_ST;
    int t = threadIdx.x;
    int lane = t & 63, wv = t >> 6;
    int q = lane >> 4, l15 = lane & 15;
    int m0 = (wv & 1) << 5, n0 = (wv >> 1) << 5;

    // gate prefetch: 16 floats covering this wave's M2 output positions
    // (index pattern proven in r0/r2: wx[(m-side)*64 + (n-side)])
    float wxr[2][2][4];
    #pragma unroll
    for (int ti = 0; ti < 2; ++ti)
        #pragma unroll
        for (int u = 0; u < 2; ++u)
            #pragma unroll
            for (int r = 0; r < 4; ++r)
                wxr[ti][u][r] = wx[(m0 + (ti << 4) + (q << 2) + r) * 64
                                   + n0 + (u << 4) + l15];

    // stage cos (swizzled) - shared by all 4 waves, never overwritten
    {
        int r = t >> 2, cb = (t & 3) << 4;
        #pragma unroll
        for (int p = 0; p < 2; ++p) {
            int chunk = (cb >> 3) + p;
            int a = (r << 7) + (((chunk ^ (r & 7)) << 4));
            *(uint4*)((char*)Ch + a) = *(const uint4*)&cos_hi[r * 64 + cb + p * 8];
            *(uint4*)((char*)Cl + a) = *(const uint4*)&cos_lo[r * 64 + cb + p * 8];
        }
    }
    // stage D = P^T (thread: col w=t&63, 16 h's), split hi/lo, swizzled
    {
        int w = t & 63, h0 = (t >> 6) << 4;
        float v[16];
        #pragma unroll
        for (int j = 0; j < 16; ++j) v[j] = po[(h0 + j) * 64 + w];
        #pragma unroll
        for (int gg = 0; gg < 4; ++gg) {
            int col = h0 + (gg << 2);
            int a = swa(w, col);
            us4 hv, lv;
            #pragma unroll
            for (int r = 0; r < 4; ++r) {
                float f = v[(gg << 2) + r];
                hv[r] = bfhi(f);
                lv[r] = bfhi(f - hif(f));
            }
            *(us4*)((char*)Dh + a) = hv;
            *(us4*)((char*)Dl + a) = lv;
        }
    }
    __syncthreads();

    short8 af[2][2][2];   // this wave's D fragments (rows base..base+31)
    f32x4 acc[2][2];
    const f32x4 zacc = {0.f, 0.f, 0.f, 0.f};

    // load this wave's D fragments (rows base..base+31) into registers
#define LOAD_D(base)                                                          \
    _Pragma("unroll")                                                         \
    for (int tt = 0; tt < 2; ++tt)                                            \
        _Pragma("unroll")                                                     \
        for (int kb = 0; kb < 2; ++kb) {                                      \
            af[tt][kb][0] = fragrd(Dh, (base) + (tt << 4) + l15, (kb << 2) + q); \
            af[tt][kb][1] = fragrd(Dl, (base) + (tt << 4) + l15, (kb << 2) + q); \
        }

    // acc[m][n] = sum_k af[m][k] * C[n][k]   (A in regs, B = cos from LDS)
#define QMM_AC()                                                              \
    acc[0][0] = zacc; acc[0][1] = zacc; acc[1][0] = zacc; acc[1][1] = zacc;   \
    __builtin_amdgcn_s_setprio(1);                                            \
    _Pragma("unroll")                                                         \
    for (int kb = 0; kb < 2; ++kb) {                                          \
        int kc = (kb << 2) + q;                                               \
        short8 b0h = fragrd(Ch, n0 + l15, kc);                                \
        short8 b0l = fragrd(Cl, n0 + l15, kc);                                \
        short8 b1h = fragrd(Ch, n0 + 16 + l15, kc);                           \
        short8 b1l = fragrd(Cl, n0 + 16 + l15, kc);                           \
        acc[0][0] = mm3(af[0][kb][0], af[0][kb][1], b0h, b0l, acc[0][0]);     \
        acc[0][1] = mm3(af[0][kb][0], af[0][kb][1], b1h, b1l, acc[0][1]);     \
        acc[1][0] = mm3(af[1][kb][0], af[1][kb][1], b0h, b0l, acc[1][0]);     \
        acc[1][1] = mm3(af[1][kb][0], af[1][kb][1], b1h, b1l, acc[1][1]);     \
    }                                                                         \
    __builtin_amdgcn_s_setprio(0);

    // acc[m][n] = sum_k C[m][k] * af[n][k]   (A = cos from LDS, B in regs)
#define QMM_CA()                                                              \
    acc[0][0] = zacc; acc[0][1] = zacc; acc[1][0] = zacc; acc[1][1] = zacc;   \
    __builtin_amdgcn_s_setprio(1);                                            \
    _Pragma("unroll")                                                         \
    for (int kb = 0; kb < 2; ++kb) {                                          \
        int kc = (kb << 2) + q;                                               \
        short8 a0h = fragrd(Ch, m0 + l15, kc);                                \
        short8 a0l = fragrd(Cl, m0 + l15, kc);                                \
        short8 a1h = fragrd(Ch, m0 + 16 + l15, kc);                           \
        short8 a1l = fragrd(Cl, m0 + 16 + l15, kc);                           \
        acc[0][0] = mm3(a0h, a0l, af[0][kb][0], af[0][kb][1], acc[0][0]);     \
        acc[0][1] = mm3(a0h, a0l, af[1][kb][0], af[1][kb][1], acc[0][1]);     \
        acc[1][0] = mm3(a1h, a1l, af[0][kb][0], af[0][kb][1], acc[1][0]);     \
        acc[1][1] = mm3(a1h, a1l, af[1][kb][0], af[1][kb][1], acc[1][1]);     \
    }                                                                         \
    __builtin_amdgcn_s_setprio(0);

    // transposed write-back: D[n-side][m-side] = acc
#define WB_T()                                                                \
    _Pragma("unroll")                                                         \
    for (int ti = 0; ti < 2; ++ti)                                            \
        _Pragma("unroll")                                                     \
        for (int u = 0; u < 2; ++u) {                                         \
            int row = n0 + (u << 4) + l15;                                    \
            int col = m0 + (ti << 4) + (q << 2);                              \
            int a = swa(row, col);                                            \
            us4 hv, lv;                                                       \
            _Pragma("unroll")                                                 \
            for (int r = 0; r < 4; ++r) {                                     \
                float f = acc[ti][u][r];                                      \
                hv[r] = bfhi(f);                                              \
                lv[r] = bfhi(f - hif(f));                                     \
            }                                                                 \
            *(us4*)((char*)Dh + a) = hv;                                      \
            *(us4*)((char*)Dl + a) = lv;                                      \
        }

    // ---- M1: D <- (D*C^T)^T   (D becomes C*P)
    LOAD_D(m0)
    __syncthreads();
    QMM_AC()
    WB_T()
    __syncthreads();

    // ---- M2: D <- ((D*C^T) .* W)^T   (gate C*P*C^T with wexp)
    LOAD_D(m0)
    __syncthreads();
    QMM_AC()
    #pragma unroll
    for (int ti = 0; ti < 2; ++ti)
        #pragma unroll
        for (int u = 0; u < 2; ++u)
            #pragma unroll
            for (int r = 0; r < 4; ++r)
                acc[ti][u][r] *= wxr[ti][u][r];
    WB_T()
    __syncthreads();

    // ---- M3: D <- C*D^T (row-major u16 scatter)
    LOAD_D(n0)
    __syncthreads();
    QMM_CA()
    #pragma unroll
    for (int ti = 0; ti < 2; ++ti)
        #pragma unroll
        for (int u = 0; u < 2; ++u)
            #pragma unroll
            for (int r = 0; r < 4; ++r) {
                int row = m0 + (ti << 4) + (q << 2) + r;
                int col = n0 + (u << 4) + l15;
                int a = swa(row, col);
                float f = acc[ti][u][r];
                *(unsigned short*)((char*)Dh + a) = bfhi(f);
                *(unsigned short*)((char*)Dl + a) = bfhi(f - hif(f));
            }
    __syncthreads();

    // ---- M4: po <- D*C^T (in place to global)
    LOAD_D(m0)
    __syncthreads();
    QMM_AC()
    #pragma unroll
    for (int ti = 0; ti < 2; ++ti)
        #pragma unroll
        for (int u = 0; u < 2; ++u)
            #pragma unroll
            for (int r = 0; r < 4; ++r) {
                int h = m0 + (ti << 4) + (q << 2) + r;
                int w = n0 + (u << 4) + l15;
                po[h * 64 + w] = acc[ti][u][r];
            }
#undef LOAD_D
#undef QMM_AC
#undef QMM_CA
#undef WB_T
}

// ---------------- k_out: out = ((LN(t)*g_o+b_o)*siluz)@Wo + bo, 4h/block pipelined ----------------
__global__ __launch_bounds__(256, 3) void k_out(
    const float* __restrict__ planes, const float* __restrict__ siluzT,
    const float* __restrict__ g_o, const float* __restrict__ b_o,
    const unsigned short* __restrict__ WoTh_g, const unsigned short* __restrict__ WoTl_g,
    const float* __restrict__ bo, float* __restrict__ out) {
    __shared__ __align__(16) short Ah[2][4096], Al[2][4096];
    __shared__ __align__(16) float red1[4][64], red2[4][64];
    __shared__ float muS[64], rsS[64];
    int b = blockIdx.x >> 4, h0 = (blockIdx.x & 15) << 2;
    int t = threadIdx.x;
    int lane = t & 63, wv = t >> 6;
    int q = lane >> 4, l15 = lane & 15;
    int m0 = (wv & 1) << 5, n0 = (wv >> 1) << 5;
    // B fragments (Wo^T) -> registers
    short8 bf[2][2][2];
    #pragma unroll
    for (int u = 0; u < 2; ++u)
        #pragma unroll
        for (int kb = 0; kb < 2; ++kb) {
            int off = (n0 + (u << 4) + l15) * 64 + ((kb << 2) + q) * 8;
            bf[u][kb][0] = *(const short8*)&WoTh_g[off];
            bf[u][kb][1] = *(const short8*)&WoTl_g[off];
        }
    int g = t >> 4, w0 = (t & 15) << 2, c0 = g << 2;
    float4 pr[2][4], sz[2][4];
    #pragma unroll
    for (int pi = 0; pi < 2; ++pi) {
        int h = h0 + pi;
        #pragma unroll
        for (int i = 0; i < 4; ++i) {
            pr[pi][i] = *(const float4*)&planes[(size_t)(b * 64 + c0 + i) * PL_ST + h * 64 + w0];
            sz[pi][i] = *(const float4*)&siluzT[(size_t)(c0 + i) * TC_ST + h * 64 + w0];
        }
    }
    #pragma unroll
    for (int it = 0; it < 4; ++it) {
        int s = it & 1;
        int h = h0 + it;
        float4 s1 = {0, 0, 0, 0}, s2 = {0, 0, 0, 0};
        #pragma unroll
        for (int i = 0; i < 4; ++i) {
            float4 tv = pr[s][i];
            s1.x += tv.x; s1.y += tv.y; s1.z += tv.z; s1.w += tv.w;
            s2.x += tv.x * tv.x; s2.y += tv.y * tv.y;
            s2.z += tv.z * tv.z; s2.w += tv.w * tv.w;
        }
        #pragma unroll
        for (int r = 0; r < 4; ++r) {
            float a1 = ((const float*)&s1)[r];
            float a2 = ((const float*)&s2)[r];
            a1 += __shfl_xor(a1, 16, 64); a1 += __shfl_xor(a1, 32, 64);
            a2 += __shfl_xor(a2, 16, 64); a2 += __shfl_xor(a2, 32, 64);
            ((float*)&s1)[r] = a1;
            ((float*)&s2)[r] = a2;
        }
        if (lane < 16) {
            *(float4*)&red1[wv][lane << 2] = s1;
            *(float4*)&red2[wv][lane << 2] = s2;
        }
        __syncthreads();
        if (t < 64) {
            float a1 = red1[0][t] + red1[1][t] + red1[2][t] + red1[3][t];
            float a2 = red2[0][t] + red2[1][t] + red2[2][t] + red2[3][t];
            float mu = a1 * (1.0f / 64.0f);
            float var = a2 * (1.0f / 64.0f) - mu * mu;
            muS[t] = mu; rsS[t] = rsqrtf(var + 1e-5f);
        }
        __syncthreads();
        // gate + split + transpose-write A[s]
        {
            float4 mu4 = *(const float4*)&muS[w0];
            float4 rs4 = *(const float4*)&rsS[w0];
            float4 vr[4];
            #pragma unroll
            for (int i = 0; i < 4; ++i) {
                int cc = c0 + i;
                float go = g_o[cc], boc = b_o[cc];
                float4 tv = pr[s][i], sv = sz[s][i];
                vr[i].x = ((tv.x - mu4.x) * rs4.x * go + boc) * sv.x;
                vr[i].y = ((tv.y - mu4.y) * rs4.y * go + boc) * sv.y;
                vr[i].z = ((tv.z - mu4.z) * rs4.z * go + boc) * sv.z;
                vr[i].w = ((tv.w - mu4.w) * rs4.w * go + boc) * sv.w;
            }
            const float* vp = (const float*)vr;
            #pragma unroll
            for (int j = 0; j < 4; ++j) {
                us4 hv, lv;
                #pragma unroll
                for (int r = 0; r < 4; ++r) {
                    float f = vp[r * 4 + j];
                    hv[r] = bfhi(f);
                    lv[r] = bfhi(f - hif(f));
                }
                int a = swa(w0 + j, c0);
                *(us4*)((char*)Ah[s] + a) = hv;
                *(us4*)((char*)Al[s] + a) = lv;
            }
        }
        // prefetch h+2 into the just-consumed slot
        if (it < 2) {
            int hn = h0 + it + 2;
            #pragma unroll
            for (int i = 0; i < 4; ++i) {
                pr[s][i] = *(const float4*)&planes[(size_t)(b * 64 + c0 + i) * PL_ST + hn * 64 + w0];
                sz[s][i] = *(const float4*)&siluzT[(size_t)(c0 + i) * TC_ST + hn * 64 + w0];
            }
        }
        __syncthreads();
        f32x4 acc[2][2];
        mm_block_regB(Ah[s], Al[s], bf, m0, l15, q, acc);
        #pragma unroll
        for (int u = 0; u < 2; ++u) {
            int o_ = n0 + (u << 4) + l15;
            float bov = bo[o_];
            #pragma unroll
            for (int ti = 0; ti < 2; ++ti) {
                int wb = m0 + (ti << 4) + (q << 2);
                float4 o;
                o.x = acc[ti][u][0] + bov;
                o.y = acc[ti][u][1] + bov;
                o.z = acc[ti][u][2] + bov;
                o.w = acc[ti][u][3] + bov;
                *(float4*)&out[((size_t)(b * 64 + o_) * 64 + h) * 64 + wb] = o;
            }
        }
    }
}

extern "C" void kernel_launch(void* const* d_in, const int* in_sizes, int n_in,
                              void* d_out, int out_size, void* d_ws, size_t ws_size,
                              hipStream_t stream) {
    const float* x    = (const float*)d_in[0];
    const float* freq = (const float*)d_in[1];
    const float* g_k  = (const float*)d_in[2];
    const float* b_k  = (const float*)d_in[3];
    const float* Wk   = (const float*)d_in[4];
    const float* bk   = (const float*)d_in[5];
    const float* g_z  = (const float*)d_in[6];
    const float* b_z  = (const float*)d_in[7];
    const float* Wz   = (const float*)d_in[8];
    const float* bz   = (const float*)d_in[9];
    const float* g_o  = (const float*)d_in[10];
    const float* b_o  = (const float*)d_in[11];
    const float* Wo   = (const float*)d_in[12];
    const float* bo   = (const float*)d_in[13];
    float* out = (float*)d_out;

    float* ws = (float*)d_ws;
    float* planes = ws;                                   // 4096*PL_ST f
    float* siluzT = planes + (size_t)4096 * PL_ST;        // 64*TC_ST f
    float* wexpT  = siluzT + (size_t)64 * TC_ST;
    float* freqT  = wexpT + (size_t)64 * TC_ST;
    float* su_k   = freqT + (size_t)64 * TC_ST;           // 64
    float* v_k    = su_k + 64;
    float* su_z   = v_k + 64;
    float* v_z    = su_z + 64;
    unsigned short* cos_hi = (unsigned short*)(v_z + 64); // 4096 u16 each
    unsigned short* cos_lo = cos_hi + 4096;
    unsigned short* WkTh = cos_lo + 4096;
    unsigned short* WkTl = WkTh + 4096;
    unsigned short* WzTh = WkTl + 4096;
    unsigned short* WzTl = WzTh + 4096;
    unsigned short* WoTh = WzTl + 4096;
    unsigned short* WoTl = WoTh + 4096;

    k_pre1<<<32, 256, 0, stream>>>(g_k, b_k, Wk, bk, g_z, b_z, Wz, bz, Wo,
                                   WkTh, WkTl, su_k, v_k, WzTh, WzTl, su_z, v_z,
                                   WoTh, WoTl, cos_hi, cos_lo);
    k_pre2<<<128, 256, 0, stream>>>(freq, WzTh, WzTl, su_z, v_z, siluzT, wexpT, freqT);
    k_k<<<1024, 256, 0, stream>>>(x, freqT, WkTh, WkTl, su_k, v_k, planes);
    k_spec<<<4096, 256, 0, stream>>>(planes, cos_hi, cos_lo, wexpT);
    k_out<<<1024, 256, 0, stream>>>(planes, siluzT, g_o, b_o, WoTh, WoTl, bo, out);
}

// Round 6
// 222.769 us; speedup vs baseline: 1.0457x; 1.0271x over previous
//
#include <hip/hip_runtime.h>

// Heat2D: B=C=H=W=KD=64. All big matmuls via split-bf16 (hi/lo) MFMA,
// LN folded into matmul epilogues where possible.
// r6 = r3-verified envelope (padded strides, 4h-pipeline k_k/k_out with
// shuffle-stats LN + B-in-regs, 4-wave single-D k_spec, UNCHUNKED launches)
// plus two orthogonal changes:
//  (1) RNE split-bf16 (round-to-nearest-even on hi AND lo) everywhere,
//      replacing truncate-truncate. Kills the coherent truncation bias that
//      put absmax at ~1-3e-5 (threshold 2.37e-5); predicted ~1-3e-6.
//  (2) planes re-laid as [b][h][c][w] (16KB slab per (b,h), stride PL_ST):
//      k_k WRITES and k_out READS become block-contiguous 16KB (they face
//      HBM); k_spec's strided access moves to L3-hot traffic it can absorb.
//      k_k's 16KB-strided write pattern was the one constant across all
//      rounds where k_k sat invariant at ~41us / 2.4TB/s effective.

#define PL_ST 4160   // padded slab stride for planes[b][h] (floats)
#define TC_ST 4160   // padded per-c stride for [c][h][w] buffers (floats)

typedef __attribute__((ext_vector_type(8))) short short8;
typedef __attribute__((ext_vector_type(4))) float f32x4;
typedef __attribute__((ext_vector_type(4))) unsigned short us4;

// round-to-nearest-even bf16 (standard +0x7FFF + lsb carry trick)
__device__ __forceinline__ unsigned short bfrnd(float f) {
    unsigned int u = __builtin_bit_cast(unsigned int, f);
    u += 0x7FFFu + ((u >> 16) & 1u);
    return (unsigned short)(u >> 16);
}
// split f ~= hi + lo with RNE on both halves (error ~2^-18 |f|, unbiased)
__device__ __forceinline__ void bfsplit(float f, unsigned short& hi, unsigned short& lo) {
    unsigned short h = bfrnd(f);
    float fh = __builtin_bit_cast(float, (unsigned int)h << 16);
    hi = h;
    lo = bfrnd(f - fh);
}
// swizzled byte address in 64x64 bf16 row-major buffer (128B rows, 16B chunks
// XOR'd with row&7): bank-uniform for b128 frag reads and b64/u16 writes.
__device__ __forceinline__ int swa(int row, int col) {
    return (row << 7) + (((col >> 3) ^ (row & 7)) << 4) + ((col & 7) << 1);
}
__device__ __forceinline__ short8 fragrd(const short* buf, int row, int kc) {
    int a = (row << 7) + ((kc ^ (row & 7)) << 4);
    return *(const short8*)((const char*)buf + a);
}
// 3-term split-bf16 product accumulate: ah*bh + ah*bl + al*bh
__device__ __forceinline__ f32x4 mm3(short8 ah, short8 al, short8 bh, short8 bl, f32x4 acc) {
    acc = __builtin_amdgcn_mfma_f32_16x16x32_bf16(ah, bh, acc, 0, 0, 0);
    acc = __builtin_amdgcn_mfma_f32_16x16x32_bf16(ah, bl, acc, 0, 0, 0);
    acc = __builtin_amdgcn_mfma_f32_16x16x32_bf16(al, bh, acc, 0, 0, 0);
    return acc;
}

// 64x64x64 matmul, 4 waves: wave computes 32x32 quadrant (2x2 16x16 tiles).
// D[m][n] = sum_k A[m][k]*B^T[n][k], 3-term split-bf16. (used by k_pre2)
__device__ __forceinline__ void mm_block(const short* Ah, const short* Al,
                                         const short* Bh, const short* Bl,
                                         int m0, int n0, int l15, int q,
                                         f32x4 (&acc)[2][2]) {
    const f32x4 zero = {0.f, 0.f, 0.f, 0.f};
    acc[0][0] = zero; acc[0][1] = zero; acc[1][0] = zero; acc[1][1] = zero;
    #pragma unroll
    for (int kb = 0; kb < 2; ++kb) {
        int kc = (kb << 2) + q;
        short8 a0h = fragrd(Ah, m0 + l15, kc);
        short8 a0l = fragrd(Al, m0 + l15, kc);
        short8 a1h = fragrd(Ah, m0 + 16 + l15, kc);
        short8 a1l = fragrd(Al, m0 + 16 + l15, kc);
        short8 b0h = fragrd(Bh, n0 + l15, kc);
        short8 b0l = fragrd(Bl, n0 + l15, kc);
        short8 b1h = fragrd(Bh, n0 + 16 + l15, kc);
        short8 b1l = fragrd(Bl, n0 + 16 + l15, kc);
        acc[0][0] = mm3(a0h, a0l, b0h, b0l, acc[0][0]);
        acc[0][1] = mm3(a0h, a0l, b1h, b1l, acc[0][1]);
        acc[1][0] = mm3(a1h, a1l, b0h, b0l, acc[1][0]);
        acc[1][1] = mm3(a1h, a1l, b1h, b1l, acc[1][1]);
    }
}

// Same quadrant matmul but B fragments already in registers.
__device__ __forceinline__ void mm_block_regB(const short* Ah, const short* Al,
                                              const short8 (&bf)[2][2][2],
                                              int m0, int l15, int q,
                                              f32x4 (&acc)[2][2]) {
    const f32x4 zero = {0.f, 0.f, 0.f, 0.f};
    acc[0][0] = zero; acc[0][1] = zero; acc[1][0] = zero; acc[1][1] = zero;
    #pragma unroll
    for (int kb = 0; kb < 2; ++kb) {
        int kc = (kb << 2) + q;
        short8 a0h = fragrd(Ah, m0 + l15, kc);
        short8 a0l = fragrd(Al, m0 + l15, kc);
        short8 a1h = fragrd(Ah, m0 + 16 + l15, kc);
        short8 a1l = fragrd(Al, m0 + 16 + l15, kc);
        #pragma unroll
        for (int u = 0; u < 2; ++u) {
            acc[0][u] = mm3(a0h, a0l, bf[u][kb][0], bf[u][kb][1], acc[0][u]);
            acc[1][u] = mm3(a1h, a1l, bf[u][kb][0], bf[u][kb][1], acc[1][u]);
        }
    }
}

// ---------------- k_pre1: weights transpose/split + LN-fold vectors + cos ----------------
__global__ __launch_bounds__(256) void k_pre1(
    const float* __restrict__ g_k, const float* __restrict__ b_k,
    const float* __restrict__ Wk, const float* __restrict__ bk,
    const float* __restrict__ g_z, const float* __restrict__ b_z,
    const float* __restrict__ Wz, const float* __restrict__ bz,
    const float* __restrict__ Wo,
    unsigned short* __restrict__ WkTh, unsigned short* __restrict__ WkTl,
    float* __restrict__ su_k, float* __restrict__ v_k,
    unsigned short* __restrict__ WzTh, unsigned short* __restrict__ WzTl,
    float* __restrict__ su_z, float* __restrict__ v_z,
    unsigned short* __restrict__ WoTh, unsigned short* __restrict__ WoTl,
    unsigned short* __restrict__ cos_hi, unsigned short* __restrict__ cos_lo) {
    int t = threadIdx.x;
    if (blockIdx.x < 16) {
        int n = blockIdx.x * 4 + (t >> 6);
        int c = t & 63;
        unsigned short h_, l_;
        // Wk' = g_k*Wk
        float wk = Wk[c * 64 + n];
        float a = g_k[c] * wk;
        bfsplit(a, h_, l_);
        WkTh[n * 64 + c] = h_;
        WkTl[n * 64 + c] = l_;
        float sa = a, sv = b_k[c] * wk;
        #pragma unroll
        for (int off = 32; off > 0; off >>= 1) {
            sa += __shfl_xor(sa, off, 64);
            sv += __shfl_xor(sv, off, 64);
        }
        if (c == 0) { su_k[n] = sa; v_k[n] = sv + bk[n]; }
        // Wz' = g_z*Wz
        float wz = Wz[c * 64 + n];
        float az = g_z[c] * wz;
        bfsplit(az, h_, l_);
        WzTh[n * 64 + c] = h_;
        WzTl[n * 64 + c] = l_;
        float saz = az, svz = b_z[c] * wz;
        #pragma unroll
        for (int off = 32; off > 0; off >>= 1) {
            saz += __shfl_xor(saz, off, 64);
            svz += __shfl_xor(svz, off, 64);
        }
        if (c == 0) { su_z[n] = saz; v_z[n] = svz + bz[n]; }
        // Wo^T
        float wo = Wo[c * 64 + n];
        bfsplit(wo, h_, l_);
        WoTh[n * 64 + c] = h_;
        WoTl[n * 64 + c] = l_;
    } else {
        int idx = (blockIdx.x - 16) * 256 + t;
        int i = idx >> 6, j = idx & 63;
        float ang = (float)(i * j) * 3.14159265358979323846f * (1.0f / 64.0f);
        float v = cosf(ang) * (1.0f / 64.0f);
        unsigned short h_, l_;
        bfsplit(v, h_, l_);
        cos_hi[idx] = h_;
        cos_lo[idx] = l_;
    }
}

// ---------------- k_pre2: z via MFMA (LN folded) + freq transpose ----------------
__global__ __launch_bounds__(256) void k_pre2(
    const float* __restrict__ freq,
    const unsigned short* __restrict__ WzTh_g, const unsigned short* __restrict__ WzTl_g,
    const float* __restrict__ su_z, const float* __restrict__ v_z,
    float* __restrict__ siluzT, float* __restrict__ wexpT,
    float* __restrict__ freqT) {
    __shared__ __align__(16) short Ah[4096], Al[4096], Bh[4096], Bl[4096];
    __shared__ float muS[64], rsS[64];
    __shared__ float tile[64][65];
    int t = threadIdx.x;
    if (blockIdx.x < 64) {
        int h = blockIdx.x;
        // stage B = WzT' swizzled
        #pragma unroll
        for (int p = 0; p < 2; ++p) {
            int e = t + p * 256;
            int row = e >> 3, ch = e & 7;
            int a = (row << 7) + (((ch ^ (row & 7)) << 4));
            *(uint4*)((char*)Bh + a) = *(const uint4*)&WzTh_g[row * 64 + ch * 8];
            *(uint4*)((char*)Bl + a) = *(const uint4*)&WzTl_g[row * 64 + ch * 8];
        }
        // A = freq[h][w][c] (already [w][c] row-major). thread: w=t>>2, 16 c's.
        int w = t >> 2, c0 = (t & 3) << 4;
        float4 fr[4];
        float s1 = 0.f, s2 = 0.f;
        #pragma unroll
        for (int i = 0; i < 4; ++i) {
            fr[i] = *(const float4*)&freq[(h * 64 + w) * 64 + c0 + 4 * i];
            s1 += fr[i].x + fr[i].y + fr[i].z + fr[i].w;
            s2 += fr[i].x * fr[i].x + fr[i].y * fr[i].y + fr[i].z * fr[i].z + fr[i].w * fr[i].w;
        }
        s1 += __shfl_xor(s1, 1, 64); s1 += __shfl_xor(s1, 2, 64);
        s2 += __shfl_xor(s2, 1, 64); s2 += __shfl_xor(s2, 2, 64);
        float mu = s1 * (1.0f / 64.0f);
        float var = s2 * (1.0f / 64.0f) - mu * mu;
        float rs = rsqrtf(var + 1e-5f);
        if ((t & 3) == 0) { muS[w] = mu; rsS[w] = rs; }
        const float* fp = (const float*)fr;
        #pragma unroll
        for (int i = 0; i < 4; ++i) {
            us4 hv, lv;
            #pragma unroll
            for (int r = 0; r < 4; ++r) {
                unsigned short h_, l_;
                bfsplit(fp[i * 4 + r], h_, l_);
                hv[r] = h_;
                lv[r] = l_;
            }
            int a = swa(w, c0 + 4 * i);
            *(us4*)((char*)Ah + a) = hv;
            *(us4*)((char*)Al + a) = lv;
        }
        __syncthreads();
        int lane = t & 63, wv = t >> 6;
        int q = lane >> 4, l15 = lane & 15;
        int m0 = (wv & 1) << 5, n0 = (wv >> 1) << 5;
        f32x4 acc[2][2];
        mm_block(Ah, Al, Bh, Bl, m0, n0, l15, q, acc);
        #pragma unroll
        for (int u = 0; u < 2; ++u) {
            int c = n0 + (u << 4) + l15;
            float suc = su_z[c], vc = v_z[c];
            #pragma unroll
            for (int ti = 0; ti < 2; ++ti) {
                int wb = m0 + (ti << 4) + (q << 2);
                float4 mu4 = *(const float4*)&muS[wb];
                float4 rs4 = *(const float4*)&rsS[wb];
                float4 sil, wx;
                #pragma unroll
                for (int r = 0; r < 4; ++r) {
                    float z = ((const float*)&rs4)[r] * (acc[ti][u][r] - ((const float*)&mu4)[r] * suc) + vc;
                    float lnd = -(float)(h + wb + r) * 0.015625f - 4.1588830833596718565f;
                    ((float*)&sil)[r] = z / (1.0f + expf(-z));
                    ((float*)&wx)[r] = expf(z * lnd);
                }
                size_t base = (size_t)c * TC_ST + h * 64 + wb;
                *(float4*)&siluzT[base] = sil;
                *(float4*)&wexpT[base] = wx;
            }
        }
    } else {
        // freq transpose: freqT[c][h][w] = freq[h][w][c]
        int h = blockIdx.x - 64;
        int w = t >> 2, c0 = (t & 3) << 4;
        #pragma unroll
        for (int i = 0; i < 4; ++i)
            *(float4*)&tile[w][c0 + 4 * i] = *(const float4*)&freq[(h * 64 + w) * 64 + c0 + 4 * i];
        __syncthreads();
        int w0 = (t & 15) << 2;
        #pragma unroll
        for (int p = 0; p < 4; ++p) {
            int c = (t >> 4) + 16 * p;
            float4 fv = make_float4(tile[w0][c], tile[w0 + 1][c], tile[w0 + 2][c], tile[w0 + 3][c]);
            *(float4*)&freqT[(size_t)c * TC_ST + h * 64 + w0] = fv;
        }
    }
}

// ---------------- k_k: planes[b][h][n][w] = LN(x^T+freq)@Wk', 4h/block pipelined ----------------
__global__ __launch_bounds__(256, 3) void k_k(
    const float* __restrict__ x, const float* __restrict__ freqT,
    const unsigned short* __restrict__ WkTh_g, const unsigned short* __restrict__ WkTl_g,
    const float* __restrict__ su_k, const float* __restrict__ v_k,
    float* __restrict__ planes) {
    __shared__ __align__(16) short Ah[2][4096], Al[2][4096];
    __shared__ __align__(16) float red1[4][64], red2[4][64];
    __shared__ float muS[64], rsS[64];
    int b = blockIdx.x >> 4, h0 = (blockIdx.x & 15) << 2;
    int t = threadIdx.x;
    int lane = t & 63, wv = t >> 6;
    int q = lane >> 4, l15 = lane & 15;
    int m0 = (wv & 1) << 5, n0 = (wv >> 1) << 5;
    // B fragments (Wk', LN-folded) -> registers (L2-hot; amortized over 4 h)
    short8 bf[2][2][2];
    #pragma unroll
    for (int u = 0; u < 2; ++u)
        #pragma unroll
        for (int kb = 0; kb < 2; ++kb) {
            int off = (n0 + (u << 4) + l15) * 64 + ((kb << 2) + q) * 8;
            bf[u][kb][0] = *(const short8*)&WkTh_g[off];
            bf[u][kb][1] = *(const short8*)&WkTl_g[off];
        }
    int g = t >> 4, w0 = (t & 15) << 2, c0 = g << 2;
    const float* xb = x + (size_t)b * 262144;
    // 2-deep pipeline: stage loads for h0, h0+1 up front
    float4 xr[2][4], fr[2][4];
    #pragma unroll
    for (int pi = 0; pi < 2; ++pi) {
        int h = h0 + pi;
        #pragma unroll
        for (int i = 0; i < 4; ++i) {
            xr[pi][i] = *(const float4*)&xb[(c0 + i) * 4096 + h * 64 + w0];
            fr[pi][i] = *(const float4*)&freqT[(size_t)(c0 + i) * TC_ST + h * 64 + w0];
        }
    }
    #pragma unroll
    for (int it = 0; it < 4; ++it) {
        int s = it & 1;
        int h = h0 + it;
        // xin = x + freqT; sums
        float4 vv[4];
        float4 s1 = {0, 0, 0, 0}, s2 = {0, 0, 0, 0};
        #pragma unroll
        for (int i = 0; i < 4; ++i) {
            float4 a = xr[s][i], f = fr[s][i];
            a.x += f.x; a.y += f.y; a.z += f.z; a.w += f.w;
            vv[i] = a;
            s1.x += a.x; s1.y += a.y; s1.z += a.z; s1.w += a.w;
            s2.x += a.x * a.x; s2.y += a.y * a.y; s2.z += a.z * a.z; s2.w += a.w * a.w;
        }
        // split + transpose-write A[s] = xinT[w][c]
        const float* vp = (const float*)vv;
        #pragma unroll
        for (int j = 0; j < 4; ++j) {
            us4 hv, lv;
            #pragma unroll
            for (int r = 0; r < 4; ++r) {
                unsigned short h_, l_;
                bfsplit(vp[r * 4 + j], h_, l_);
                hv[r] = h_;
                lv[r] = l_;
            }
            int a = swa(w0 + j, c0);
            *(us4*)((char*)Ah[s] + a) = hv;
            *(us4*)((char*)Al[s] + a) = lv;
        }
        // stats: in-wave shuffle over the wave's 4 c-groups, then 4-deep LDS
        #pragma unroll
        for (int r = 0; r < 4; ++r) {
            float a1 = ((const float*)&s1)[r];
            float a2 = ((const float*)&s2)[r];
            a1 += __shfl_xor(a1, 16, 64); a1 += __shfl_xor(a1, 32, 64);
            a2 += __shfl_xor(a2, 16, 64); a2 += __shfl_xor(a2, 32, 64);
            ((float*)&s1)[r] = a1;
            ((float*)&s2)[r] = a2;
        }
        if (lane < 16) {
            *(float4*)&red1[wv][lane << 2] = s1;
            *(float4*)&red2[wv][lane << 2] = s2;
        }
        __syncthreads();
        if (t < 64) {
            float a1 = red1[0][t] + red1[1][t] + red1[2][t] + red1[3][t];
            float a2 = red2[0][t] + red2[1][t] + red2[2][t] + red2[3][t];
            float mu = a1 * (1.0f / 64.0f);
            float var = a2 * (1.0f / 64.0f) - mu * mu;
            muS[t] = mu; rsS[t] = rsqrtf(var + 1e-5f);
        }
        __syncthreads();
        // prefetch h+2 into the just-consumed slot (hides HBM under MFMA+next split)
        if (it < 2) {
            int hn = h0 + it + 2;
            #pragma unroll
            for (int i = 0; i < 4; ++i) {
                xr[s][i] = *(const float4*)&xb[(c0 + i) * 4096 + hn * 64 + w0];
                fr[s][i] = *(const float4*)&freqT[(size_t)(c0 + i) * TC_ST + hn * 64 + w0];
            }
        }
        f32x4 acc[2][2];
        mm_block_regB(Ah[s], Al[s], bf, m0, l15, q, acc);
        // write slab (b,h): contiguous 16KB per block
        float* slab = planes + (size_t)(b * 64 + h) * PL_ST;
        #pragma unroll
        for (int u = 0; u < 2; ++u) {
            int n = n0 + (u << 4) + l15;
            float sun = su_k[n], vn = v_k[n];
            #pragma unroll
            for (int ti = 0; ti < 2; ++ti) {
                int wb = m0 + (ti << 4) + (q << 2);
                float4 mu4 = *(const float4*)&muS[wb];
                float4 rs4 = *(const float4*)&rsS[wb];
                float4 o;
                o.x = rs4.x * (acc[ti][u][0] - mu4.x * sun) + vn;
                o.y = rs4.y * (acc[ti][u][1] - mu4.y * sun) + vn;
                o.z = rs4.z * (acc[ti][u][2] - mu4.z * sun) + vn;
                o.w = rs4.w * (acc[ti][u][3] - mu4.w * sun) + vn;
                *(float4*)&slab[n * 64 + wb] = o;
            }
        }
    }
}

// ---------------- k_spec: 4 waves/plane, single in-place D buffer ----------------
__global__ __launch_bounds__(256, 4) void k_spec(
    float* __restrict__ planes,
    const unsigned short* __restrict__ cos_hi, const unsigned short* __restrict__ cos_lo,
    const float* __restrict__ wexpT) {
    __shared__ __align__(16) short Ch[4096], Cl[4096];
    __shared__ __align__(16) short Dh[4096], Dl[4096];
    int bid = blockIdx.x;
    int b = bid >> 6, c = bid & 63;
    // plane (b,c) lives at column c*64 of slabs (b*64+h), h=0..63
    float* pb = planes + (size_t)b * 64 * PL_ST + c * 64;
    const float* wx = wexpT + (size_t)c * TC_ST;
    int t = threadIdx.x;
    int lane = t & 63, wv = t >> 6;
    int q = lane >> 4, l15 = lane & 15;
    int m0 = (wv & 1) << 5, n0 = (wv >> 1) << 5;

    // gate prefetch: 16 floats covering this wave's M2 output positions
    float wxr[2][2][4];
    #pragma unroll
    for (int ti = 0; ti < 2; ++ti)
        #pragma unroll
        for (int u = 0; u < 2; ++u)
            #pragma unroll
            for (int r = 0; r < 4; ++r)
                wxr[ti][u][r] = wx[(m0 + (ti << 4) + (q << 2) + r) * 64
                                   + n0 + (u << 4) + l15];

    // stage cos (swizzled) - shared by all 4 waves, never overwritten
    {
        int r = t >> 2, cb = (t & 3) << 4;
        #pragma unroll
        for (int p = 0; p < 2; ++p) {
            int chunk = (cb >> 3) + p;
            int a = (r << 7) + (((chunk ^ (r & 7)) << 4));
            *(uint4*)((char*)Ch + a) = *(const uint4*)&cos_hi[r * 64 + cb + p * 8];
            *(uint4*)((char*)Cl + a) = *(const uint4*)&cos_lo[r * 64 + cb + p * 8];
        }
    }
    // stage D = P^T (thread: col w=t&63, 16 h's), split hi/lo, swizzled
    {
        int w = t & 63, h0 = (t >> 6) << 4;
        float v[16];
        #pragma unroll
        for (int j = 0; j < 16; ++j) v[j] = pb[(size_t)(h0 + j) * PL_ST + w];
        #pragma unroll
        for (int gg = 0; gg < 4; ++gg) {
            int col = h0 + (gg << 2);
            int a = swa(w, col);
            us4 hv, lv;
            #pragma unroll
            for (int r = 0; r < 4; ++r) {
                unsigned short h_, l_;
                bfsplit(v[(gg << 2) + r], h_, l_);
                hv[r] = h_;
                lv[r] = l_;
            }
            *(us4*)((char*)Dh + a) = hv;
            *(us4*)((char*)Dl + a) = lv;
        }
    }
    __syncthreads();

    short8 af[2][2][2];   // this wave's D fragments (rows base..base+31)
    f32x4 acc[2][2];
    const f32x4 zacc = {0.f, 0.f, 0.f, 0.f};

#define LOAD_D(base)                                                          \
    _Pragma("unroll")                                                         \
    for (int tt = 0; tt < 2; ++tt)                                            \
        _Pragma("unroll")                                                     \
        for (int kb = 0; kb < 2; ++kb) {                                      \
            af[tt][kb][0] = fragrd(Dh, (base) + (tt << 4) + l15, (kb << 2) + q); \
            af[tt][kb][1] = fragrd(Dl, (base) + (tt << 4) + l15, (kb << 2) + q); \
        }

#define QMM_AC()                                                              \
    acc[0][0] = zacc; acc[0][1] = zacc; acc[1][0] = zacc; acc[1][1] = zacc;   \
    __builtin_amdgcn_s_setprio(1);                                            \
    _Pragma("unroll")                                                         \
    for (int kb = 0; kb < 2; ++kb) {                                          \
        int kc = (kb << 2) + q;                                               \
        short8 b0h = fragrd(Ch, n0 + l15, kc);                                \
        short8 b0l = fragrd(Cl, n0 + l15, kc);                                \
        short8 b1h = fragrd(Ch, n0 + 16 + l15, kc);                           \
        short8 b1l = fragrd(Cl, n0 + 16 + l15, kc);                           \
        acc[0][0] = mm3(af[0][kb][0], af[0][kb][1], b0h, b0l, acc[0][0]);     \
        acc[0][1] = mm3(af[0][kb][0], af[0][kb][1], b1h, b1l, acc[0][1]);     \
        acc[1][0] = mm3(af[1][kb][0], af[1][kb][1], b0h, b0l, acc[1][0]);     \
        acc[1][1] = mm3(af[1][kb][0], af[1][kb][1], b1h, b1l, acc[1][1]);     \
    }                                                                         \
    __builtin_amdgcn_s_setprio(0);

#define QMM_CA()                                                              \
    acc[0][0] = zacc; acc[0][1] = zacc; acc[1][0] = zacc; acc[1][1] = zacc;   \
    __builtin_amdgcn_s_setprio(1);                                            \
    _Pragma("unroll")                                                         \
    for (int kb = 0; kb < 2; ++kb) {                                          \
        int kc = (kb << 2) + q;                                               \
        short8 a0h = fragrd(Ch, m0 + l15, kc);                                \
        short8 a0l = fragrd(Cl, m0 + l15, kc);                                \
        short8 a1h = fragrd(Ch, m0 + 16 + l15, kc);                           \
        short8 a1l = fragrd(Cl, m0 + 16 + l15, kc);                           \
        acc[0][0] = mm3(a0h, a0l, af[0][kb][0], af[0][kb][1], acc[0][0]);     \
        acc[0][1] = mm3(a0h, a0l, af[1][kb][0], af[1][kb][1], acc[0][1]);     \
        acc[1][0] = mm3(a1h, a1l, af[0][kb][0], af[0][kb][1], acc[1][0]);     \
        acc[1][1] = mm3(a1h, a1l, af[1][kb][0], af[1][kb][1], acc[1][1]);     \
    }                                                                         \
    __builtin_amdgcn_s_setprio(0);

#define WB_T()                                                                \
    _Pragma("unroll")                                                         \
    for (int ti = 0; ti < 2; ++ti)                                            \
        _Pragma("unroll")                                                     \
        for (int u = 0; u < 2; ++u) {                                         \
            int row = n0 + (u << 4) + l15;                                    \
            int col = m0 + (ti << 4) + (q << 2);                              \
            int a = swa(row, col);                                            \
            us4 hv, lv;                                                       \
            _Pragma("unroll")                                                 \
            for (int r = 0; r < 4; ++r) {                                     \
                unsigned short h_, l_;                                        \
                bfsplit(acc[ti][u][r], h_, l_);                               \
                hv[r] = h_;                                                   \
                lv[r] = l_;                                                   \
            }                                                                 \
            *(us4*)((char*)Dh + a) = hv;                                      \
            *(us4*)((char*)Dl + a) = lv;                                      \
        }

    // ---- M1: D <- (D*C^T)^T   (D becomes C*P)
    LOAD_D(m0)
    __syncthreads();
    QMM_AC()
    WB_T()
    __syncthreads();

    // ---- M2: D <- ((D*C^T) .* W)^T   (gate C*P*C^T with wexp)
    LOAD_D(m0)
    __syncthreads();
    QMM_AC()
    #pragma unroll
    for (int ti = 0; ti < 2; ++ti)
        #pragma unroll
        for (int u = 0; u < 2; ++u)
            #pragma unroll
            for (int r = 0; r < 4; ++r)
                acc[ti][u][r] *= wxr[ti][u][r];
    WB_T()
    __syncthreads();

    // ---- M3: D <- C*D^T (row-major u16 scatter)
    LOAD_D(n0)
    __syncthreads();
    QMM_CA()
    #pragma unroll
    for (int ti = 0; ti < 2; ++ti)
        #pragma unroll
        for (int u = 0; u < 2; ++u)
            #pragma unroll
            for (int r = 0; r < 4; ++r) {
                int row = m0 + (ti << 4) + (q << 2) + r;
                int col = n0 + (u << 4) + l15;
                int a = swa(row, col);
                unsigned short h_, l_;
                bfsplit(acc[ti][u][r], h_, l_);
                *(unsigned short*)((char*)Dh + a) = h_;
                *(unsigned short*)((char*)Dl + a) = l_;
            }
    __syncthreads();

    // ---- M4: pb <- D*C^T (in place to global, slab layout)
    LOAD_D(m0)
    __syncthreads();
    QMM_AC()
    #pragma unroll
    for (int ti = 0; ti < 2; ++ti)
        #pragma unroll
        for (int u = 0; u < 2; ++u)
            #pragma unroll
            for (int r = 0; r < 4; ++r) {
                int h = m0 + (ti << 4) + (q << 2) + r;
                int w = n0 + (u << 4) + l15;
                pb[(size_t)h * PL_ST + w] = acc[ti][u][r];
            }
#undef LOAD_D
#undef QMM_AC
#undef QMM_CA
#undef WB_T
}

// ---------------- k_out: out = ((LN(t)*g_o+b_o)*siluz)@Wo + bo, 4h/block pipelined ----------------
__global__ __launch_bounds__(256, 3) void k_out(
    const float* __restrict__ planes, const float* __restrict__ siluzT,
    const float* __restrict__ g_o, const float* __restrict__ b_o,
    const unsigned short* __restrict__ WoTh_g, const unsigned short* __restrict__ WoTl_g,
    const float* __restrict__ bo, float* __restrict__ out) {
    __shared__ __align__(16) short Ah[2][4096], Al[2][4096];
    __shared__ __align__(16) float red1[4][64], red2[4][64];
    __shared__ float muS[64], rsS[64];
    int b = blockIdx.x >> 4, h0 = (blockIdx.x & 15) << 2;
    int t = threadIdx.x;
    int lane = t & 63, wv = t >> 6;
    int q = lane >> 4, l15 = lane & 15;
    int m0 = (wv & 1) << 5, n0 = (wv >> 1) << 5;
    // B fragments (Wo^T) -> registers
    short8 bf[2][2][2];
    #pragma unroll
    for (int u = 0; u < 2; ++u)
        #pragma unroll
        for (int kb = 0; kb < 2; ++kb) {
            int off = (n0 + (u << 4) + l15) * 64 + ((kb << 2) + q) * 8;
            bf[u][kb][0] = *(const short8*)&WoTh_g[off];
            bf[u][kb][1] = *(const short8*)&WoTl_g[off];
        }
    int g = t >> 4, w0 = (t & 15) << 2, c0 = g << 2;
    float4 pr[2][4], sz[2][4];
    #pragma unroll
    for (int pi = 0; pi < 2; ++pi) {
        int h = h0 + pi;
        const float* slab = planes + (size_t)(b * 64 + h) * PL_ST;
        #pragma unroll
        for (int i = 0; i < 4; ++i) {
            pr[pi][i] = *(const float4*)&slab[(c0 + i) * 64 + w0];
            sz[pi][i] = *(const float4*)&siluzT[(size_t)(c0 + i) * TC_ST + h * 64 + w0];
        }
    }
    #pragma unroll
    for (int it = 0; it < 4; ++it) {
        int s = it & 1;
        int h = h0 + it;
        float4 s1 = {0, 0, 0, 0}, s2 = {0, 0, 0, 0};
        #pragma unroll
        for (int i = 0; i < 4; ++i) {
            float4 tv = pr[s][i];
            s1.x += tv.x; s1.y += tv.y; s1.z += tv.z; s1.w += tv.w;
            s2.x += tv.x * tv.x; s2.y += tv.y * tv.y;
            s2.z += tv.z * tv.z; s2.w += tv.w * tv.w;
        }
        #pragma unroll
        for (int r = 0; r < 4; ++r) {
            float a1 = ((const float*)&s1)[r];
            float a2 = ((const float*)&s2)[r];
            a1 += __shfl_xor(a1, 16, 64); a1 += __shfl_xor(a1, 32, 64);
            a2 += __shfl_xor(a2, 16, 64); a2 += __shfl_xor(a2, 32, 64);
            ((float*)&s1)[r] = a1;
            ((float*)&s2)[r] = a2;
        }
        if (lane < 16) {
            *(float4*)&red1[wv][lane << 2] = s1;
            *(float4*)&red2[wv][lane << 2] = s2;
        }
        __syncthreads();
        if (t < 64) {
            float a1 = red1[0][t] + red1[1][t] + red1[2][t] + red1[3][t];
            float a2 = red2[0][t] + red2[1][t] + red2[2][t] + red2[3][t];
            float mu = a1 * (1.0f / 64.0f);
            float var = a2 * (1.0f / 64.0f) - mu * mu;
            muS[t] = mu; rsS[t] = rsqrtf(var + 1e-5f);
        }
        __syncthreads();
        // gate + split + transpose-write A[s]
        {
            float4 mu4 = *(const float4*)&muS[w0];
            float4 rs4 = *(const float4*)&rsS[w0];
            float4 vr[4];
            #pragma unroll
            for (int i = 0; i < 4; ++i) {
                int cc = c0 + i;
                float go = g_o[cc], boc = b_o[cc];
                float4 tv = pr[s][i], sv = sz[s][i];
                vr[i].x = ((tv.x - mu4.x) * rs4.x * go + boc) * sv.x;
                vr[i].y = ((tv.y - mu4.y) * rs4.y * go + boc) * sv.y;
                vr[i].z = ((tv.z - mu4.z) * rs4.z * go + boc) * sv.z;
                vr[i].w = ((tv.w - mu4.w) * rs4.w * go + boc) * sv.w;
            }
            const float* vp = (const float*)vr;
            #pragma unroll
            for (int j = 0; j < 4; ++j) {
                us4 hv, lv;
                #pragma unroll
                for (int r = 0; r < 4; ++r) {
                    unsigned short h_, l_;
                    bfsplit(vp[r * 4 + j], h_, l_);
                    hv[r] = h_;
                    lv[r] = l_;
                }
                int a = swa(w0 + j, c0);
                *(us4*)((char*)Ah[s] + a) = hv;
                *(us4*)((char*)Al[s] + a) = lv;
            }
        }
        // prefetch h+2 into the just-consumed slot
        if (it < 2) {
            int hn = h0 + it + 2;
            const float* slab = planes + (size_t)(b * 64 + hn) * PL_ST;
            #pragma unroll
            for (int i = 0; i < 4; ++i) {
                pr[s][i] = *(const float4*)&slab[(c0 + i) * 64 + w0];
                sz[s][i] = *(const float4*)&siluzT[(size_t)(c0 + i) * TC_ST + hn * 64 + w0];
            }
        }
        __syncthreads();
        f32x4 acc[2][2];
        mm_block_regB(Ah[s], Al[s], bf, m0, l15, q, acc);
        #pragma unroll
        for (int u = 0; u < 2; ++u) {
            int o_ = n0 + (u << 4) + l15;
            float bov = bo[o_];
            #pragma unroll
            for (int ti = 0; ti < 2; ++ti) {
                int wb = m0 + (ti << 4) + (q << 2);
                float4 o;
                o.x = acc[ti][u][0] + bov;
                o.y = acc[ti][u][1] + bov;
                o.z = acc[ti][u][2] + bov;
                o.w = acc[ti][u][3] + bov;
                *(float4*)&out[((size_t)(b * 64 + o_) * 64 + h) * 64 + wb] = o;
            }
        }
    }
}

extern "C" void kernel_launch(void* const* d_in, const int* in_sizes, int n_in,
                              void* d_out, int out_size, void* d_ws, size_t ws_size,
                              hipStream_t stream) {
    const float* x    = (const float*)d_in[0];
    const float* freq = (const float*)d_in[1];
    const float* g_k  = (const float*)d_in[2];
    const float* b_k  = (const float*)d_in[3];
    const float* Wk   = (const float*)d_in[4];
    const float* bk   = (const float*)d_in[5];
    const float* g_z  = (const float*)d_in[6];
    const float* b_z  = (const float*)d_in[7];
    const float* Wz   = (const float*)d_in[8];
    const float* bz   = (const float*)d_in[9];
    const float* g_o  = (const float*)d_in[10];
    const float* b_o  = (const float*)d_in[11];
    const float* Wo   = (const float*)d_in[12];
    const float* bo   = (const float*)d_in[13];
    float* out = (float*)d_out;

    float* ws = (float*)d_ws;
    float* planes = ws;                                   // 4096*PL_ST f
    float* siluzT = planes + (size_t)4096 * PL_ST;        // 64*TC_ST f
    float* wexpT  = siluzT + (size_t)64 * TC_ST;
    float* freqT  = wexpT + (size_t)64 * TC_ST;
    float* su_k   = freqT + (size_t)64 * TC_ST;           // 64
    float* v_k    = su_k + 64;
    float* su_z   = v_k + 64;
    float* v_z    = su_z + 64;
    unsigned short* cos_hi = (unsigned short*)(v_z + 64); // 4096 u16 each
    unsigned short* cos_lo = cos_hi + 4096;
    unsigned short* WkTh = cos_lo + 4096;
    unsigned short* WkTl = WkTh + 4096;
    unsigned short* WzTh = WkTl + 4096;
    unsigned short* WzTl = WzTh + 4096;
    unsigned short* WoTh = WzTl + 4096;
    unsigned short* WoTl = WoTh + 4096;

    k_pre1<<<32, 256, 0, stream>>>(g_k, b_k, Wk, bk, g_z, b_z, Wz, bz, Wo,
                                   WkTh, WkTl, su_k, v_k, WzTh, WzTl, su_z, v_z,
                                   WoTh, WoTl, cos_hi, cos_lo);
    k_pre2<<<128, 256, 0, stream>>>(freq, WzTh, WzTl, su_z, v_z, siluzT, wexpT, freqT);
    k_k<<<1024, 256, 0, stream>>>(x, freqT, WkTh, WkTl, su_k, v_k, planes);
    k_spec<<<4096, 256, 0, stream>>>(planes, cos_hi, cos_lo, wexpT);
    k_out<<<1024, 256, 0, stream>>>(planes, siluzT, g_o, b_o, WoTh, WoTl, bo, out);
}